// Round 2
// 1623.794 us; speedup vs baseline: 1.9355x; 1.9355x over previous
//
#include <hip/hip_runtime.h>
#include <hip/hip_fp16.h>

// ---------------------------------------------------------------------------
// GraphConv_8847632629923 : round 7 (round 6 had a compile typo in k_prep_all)
//   - 12x k_gemm_node + 4x k_gemm_agg (fp32 VALU SGEMM, est ~1.3-1.6 ms total)
//     rewritten on MFMA fp16 with hi/lo split (3-MFMA, fp32-equivalent
//     precision): k_node_mfma (64x128 tile, B direct from pre-transposed
//     pre-split weights), k_agg_mfma (128x128 tile, XOR-swizzled LDS
//     transpose of xw).
//   - k_prep_all: one-shot weight transpose+split into d_out attn region
//     (scratch; fully overwritten by k_attn afterwards).
//   - k_proj: XCD-bijective block swizzle so the 8 bn-blocks sharing an
//     A-tile land on ONE XCD's L2 (FETCH 422 MB -> ~130 MB predicted).
//   Everything else identical to round 5.
// ---------------------------------------------------------------------------

#define GB   256          // batch (graphs)
#define SS   200          // nodes per graph
#define KIN  200          // input features
#define HD   128          // hidden
#define NLAY 4
#define NHD  8
#define TOPK 100
#define NT   (GB * SS)    // 51200 nodes
#define EPG_ 6400
#define NE_  (GB * EPG_)  // 1,638,400 edges
#define EMB_ 512

typedef _Float16 half8 __attribute__((ext_vector_type(8)));
typedef _Float16 half4v __attribute__((ext_vector_type(4)));
typedef float floatx4 __attribute__((ext_vector_type(4)));

// ---------------- adjacency build ----------------
__global__ __launch_bounds__(256) void k_build_A(const int* __restrict__ src,
                                                 const int* __restrict__ dst,
                                                 float* __restrict__ A) {
  int e = blockIdx.x * 256 + threadIdx.x;
  if (e >= NE_) return;
  int d = dst[e], s = src[e];
  int b = d / SS;
  int dl = d - b * SS;
  int sl = s - b * SS;
  atomicAdd(&A[((size_t)b * SS + dl) * SS + sl], 1.0f);
}

// ---------------- dinv = rsqrt(in_deg + 1) ----------------
__global__ __launch_bounds__(256) void k_dinv(const float* __restrict__ A,
                                              float* __restrict__ dinv) {
  int node = blockIdx.x * 4 + (threadIdx.x >> 6);
  int lane = threadIdx.x & 63;
  const float* r = A + (size_t)node * SS;
  float v = r[lane] + r[lane + 64] + r[lane + 128];
  if (lane < 8) v += r[lane + 192];
#pragma unroll
  for (int o = 32; o; o >>= 1) v += __shfl_xor(v, o);
  if (lane == 0) dinv[node] = rsqrtf(v + 1.0f);
}

// ---------------- weight prep: transpose + fp16 hi/lo split -----------------
// 12 matrices -> Wt[n][Kpad] (n=0..127), zero-padded to Kpad. One launch.
__global__ __launch_bounds__(256) void k_prep_all(
    const float* __restrict__ gcn_w0, const float* __restrict__ gcn_w,
    const float* __restrict__ lin1_w0, const float* __restrict__ lin1_w,
    const float* __restrict__ lin2_w,
    __half* __restrict__ whi, __half* __restrict__ wlo) {
  const int mat = blockIdx.x >> 7;   // 0..11
  const int n   = blockIdx.x & 127;
  const int l = mat / 3, which = mat % 3;
  const float* src;
  int K, Kpad;
  if (which == 0) {
    K = l ? HD : KIN;  Kpad = l ? 128 : 256;
    src = l ? gcn_w + (size_t)(l - 1) * HD * HD : gcn_w0;
  } else if (which == 1) {
    K = l ? 2 * HD : KIN + HD;  Kpad = l ? 256 : 384;
    src = l ? lin1_w + (size_t)(l - 1) * 2 * HD * HD : lin1_w0;
  } else {
    K = HD;  Kpad = HD;
    src = lin2_w + (size_t)l * HD * HD;
  }
  int off = (l == 0) ? (which == 0 ? 0 : (which == 1 ? 32768 : 81920))
                     : 98304 + (l - 1) * 65536 +
                       (which == 0 ? 0 : (which == 1 ? 16384 : 49152));
  _Float16* wh = (_Float16*)whi + (size_t)off + (size_t)n * Kpad;
  _Float16* wl = (_Float16*)wlo + (size_t)off + (size_t)n * Kpad;
  for (int k = threadIdx.x; k < Kpad; k += 256) {
    float v = (k < K) ? src[(size_t)k * HD + n] : 0.f;
    _Float16 h = (_Float16)v;
    wh[k] = h;
    wl[k] = (_Float16)(v - (float)h);
  }
}

// ------- node GEMM (MFMA split-fp16): out[N,128] = act([in1|in2]@W + b) -----
// 64-row x 128-col tile, BK=64, 4 waves as 2x2 of 32x64. A staged hi/lo in
// LDS; B read directly from pre-transposed pre-split weights (L2-resident).
__global__ __launch_bounds__(256) void k_node_mfma(
    const float* __restrict__ in1, int k1,
    const float* __restrict__ in2,                 // stride HD, may be null
    const __half* __restrict__ Whi, const __half* __restrict__ Wlo,
    int Kpad,
    const float* __restrict__ bias,                // may be null
    float* __restrict__ out, int doTanh) {
  const int m0 = blockIdx.x * 64;
  const int t = threadIdx.x;
  const int wave = t >> 6, lane = t & 63;
  const int col = lane & 15, quad = lane >> 4;
  const int wm = (wave & 1) * 32;
  const int wn = (wave >> 1) * 64;
  __shared__ __align__(16) _Float16 Ah[64][72];
  __shared__ __align__(16) _Float16 Al[64][72];
  floatx4 acc[2][4] = {};
  const int lr = t >> 2;              // staging row 0..63
  const int lk = (t & 3) * 16;        // staging k offset
  const _Float16* Wh = (const _Float16*)Whi;
  const _Float16* Wl = (const _Float16*)Wlo;

  for (int k0 = 0; k0 < Kpad; k0 += 64) {
    __syncthreads();
#pragma unroll
    for (int q = 0; q < 4; ++q) {
      int kg = k0 + lk + q * 4;
      float4 v = {0.f, 0.f, 0.f, 0.f};
      if (kg < k1)
        v = *reinterpret_cast<const float4*>(&in1[(size_t)(m0 + lr) * k1 + kg]);
      else if (in2 && kg < k1 + HD)
        v = *reinterpret_cast<const float4*>(&in2[(size_t)(m0 + lr) * HD + (kg - k1)]);
      half4v h = {(_Float16)v.x, (_Float16)v.y, (_Float16)v.z, (_Float16)v.w};
      half4v lo = {(_Float16)(v.x - (float)h.x), (_Float16)(v.y - (float)h.y),
                   (_Float16)(v.z - (float)h.z), (_Float16)(v.w - (float)h.w)};
      *reinterpret_cast<half4v*>(&Ah[lr][lk + q * 4]) = h;
      *reinterpret_cast<half4v*>(&Al[lr][lk + q * 4]) = lo;
    }
    __syncthreads();
#pragma unroll
    for (int ks = 0; ks < 2; ++ks) {
      half8 ah[2], al[2], bh[4], bl[4];
#pragma unroll
      for (int i = 0; i < 2; ++i) {
        ah[i] = *reinterpret_cast<const half8*>(&Ah[wm + i * 16 + col][ks * 32 + quad * 8]);
        al[i] = *reinterpret_cast<const half8*>(&Al[wm + i * 16 + col][ks * 32 + quad * 8]);
      }
#pragma unroll
      for (int j = 0; j < 4; ++j) {
        const size_t wo = (size_t)(wn + j * 16 + col) * Kpad + k0 + ks * 32 + quad * 8;
        bh[j] = *reinterpret_cast<const half8*>(Wh + wo);
        bl[j] = *reinterpret_cast<const half8*>(Wl + wo);
      }
#pragma unroll
      for (int i = 0; i < 2; ++i)
#pragma unroll
        for (int j = 0; j < 4; ++j) {
          acc[i][j] = __builtin_amdgcn_mfma_f32_16x16x32_f16(ah[i], bh[j], acc[i][j], 0, 0, 0);
          acc[i][j] = __builtin_amdgcn_mfma_f32_16x16x32_f16(ah[i], bl[j], acc[i][j], 0, 0, 0);
          acc[i][j] = __builtin_amdgcn_mfma_f32_16x16x32_f16(al[i], bh[j], acc[i][j], 0, 0, 0);
        }
    }
  }
#pragma unroll
  for (int j = 0; j < 4; ++j) {
    int n = wn + j * 16 + col;
    float bb = bias ? bias[n] : 0.f;
#pragma unroll
    for (int i = 0; i < 2; ++i) {
      int rbase = m0 + wm + i * 16 + quad * 4;
#pragma unroll
      for (int r = 0; r < 4; ++r) {
        float v = acc[i][j][r] + bb;
        if (doTanh) v = tanhf(v);
        out[(size_t)(rbase + r) * HD + n] = v;
      }
    }
  }
}

// ------- GCN aggregation (MFMA split-fp16): x1 = tanh( Ahat @ xw + b ) ------
// 128-row x 128-col tile per (graph, half). Ahat normalized+split at staging.
// xw transposed into LDS with XOR swizzle (k ^= ((n>>2)&7)<<3) to avoid the
// 16-way column-write bank conflict.
__global__ __launch_bounds__(256) void k_agg_mfma(
    const float* __restrict__ A, const float* __restrict__ dinv,
    const float* __restrict__ xw, const float* __restrict__ bias,
    float* __restrict__ out) {
  const int b    = blockIdx.x >> 1;
  const int row0 = (blockIdx.x & 1) * 128;
  const int t = threadIdx.x;
  const int wave = t >> 6, lane = t & 63;
  const int col = lane & 15, quad = lane >> 4;
  const int wm = (wave & 1) * 64, wn = (wave >> 1) * 64;
  __shared__ __align__(16) _Float16 Ah[128][72];
  __shared__ __align__(16) _Float16 Al[128][72];
  __shared__ __align__(16) _Float16 Bh[128][72];
  __shared__ __align__(16) _Float16 Bl[128][72];
  __shared__ float dvs[256];
  dvs[t] = (t < SS) ? dinv[b * SS + t] : 0.f;
  floatx4 acc[4][4] = {};
  const float* Ab  = A  + (size_t)b * SS * SS;
  const float* xwb = xw + (size_t)b * SS * HD;
  const int lr = t >> 1, lk = (t & 1) * 32;
  const int d = row0 + lr;
  __syncthreads();
  const float dvd = (d < SS) ? dvs[d] : 0.f;

  for (int k0 = 0; k0 < 256; k0 += 64) {
    __syncthreads();
    // ---- stage Ahat rows (hi/lo) ----
#pragma unroll
    for (int q = 0; q < 8; ++q) {
      int s = k0 + lk + q * 4;
      float4 v = {0.f, 0.f, 0.f, 0.f};
      if (d < SS && s < SS)
        v = *reinterpret_cast<const float4*>(&Ab[(size_t)d * SS + s]);
      float e0 = (v.x + ((s + 0 == d) ? 1.f : 0.f)) * dvd * dvs[(s + 0) & 255];
      float e1 = (v.y + ((s + 1 == d) ? 1.f : 0.f)) * dvd * dvs[(s + 1) & 255];
      float e2 = (v.z + ((s + 2 == d) ? 1.f : 0.f)) * dvd * dvs[(s + 2) & 255];
      float e3 = (v.w + ((s + 3 == d) ? 1.f : 0.f)) * dvd * dvs[(s + 3) & 255];
      half4v h = {(_Float16)e0, (_Float16)e1, (_Float16)e2, (_Float16)e3};
      half4v lo = {(_Float16)(e0 - (float)h.x), (_Float16)(e1 - (float)h.y),
                   (_Float16)(e2 - (float)h.z), (_Float16)(e3 - (float)h.w)};
      *reinterpret_cast<half4v*>(&Ah[lr][lk + q * 4]) = h;
      *reinterpret_cast<half4v*>(&Al[lr][lk + q * 4]) = lo;
    }
    // ---- stage xw transposed (hi/lo), XOR-swizzled ----
#pragma unroll
    for (int p = 0; p < 8; ++p) {
      int idx = t + p * 256;
      int c4 = idx & 31, ss = idx >> 5;          // ss 0..63
      int s = k0 + ss;
      float4 v = {0.f, 0.f, 0.f, 0.f};
      if (s < SS)
        v = *reinterpret_cast<const float4*>(&xwb[(size_t)s * HD + c4 * 4]);
      int ssx = ss ^ ((c4 & 7) << 3);            // (n>>2)&7 == c4&7 for n=4*c4+j
      float e[4] = {v.x, v.y, v.z, v.w};
#pragma unroll
      for (int j = 0; j < 4; ++j) {
        _Float16 h = (_Float16)e[j];
        Bh[c4 * 4 + j][ssx] = h;
        Bl[c4 * 4 + j][ssx] = (_Float16)(e[j] - (float)h);
      }
    }
    __syncthreads();
#pragma unroll
    for (int ks = 0; ks < 2; ++ks) {
      half8 ah[4], al[4], bh[4], bl[4];
#pragma unroll
      for (int i = 0; i < 4; ++i) {
        ah[i] = *reinterpret_cast<const half8*>(&Ah[wm + i * 16 + col][ks * 32 + quad * 8]);
        al[i] = *reinterpret_cast<const half8*>(&Al[wm + i * 16 + col][ks * 32 + quad * 8]);
      }
#pragma unroll
      for (int j = 0; j < 4; ++j) {
        int n = wn + j * 16 + col;
        int koff = (ks * 32 + quad * 8) ^ (((n >> 2) & 7) << 3);
        bh[j] = *reinterpret_cast<const half8*>(&Bh[n][koff]);
        bl[j] = *reinterpret_cast<const half8*>(&Bl[n][koff]);
      }
#pragma unroll
      for (int i = 0; i < 4; ++i)
#pragma unroll
        for (int j = 0; j < 4; ++j) {
          acc[i][j] = __builtin_amdgcn_mfma_f32_16x16x32_f16(ah[i], bh[j], acc[i][j], 0, 0, 0);
          acc[i][j] = __builtin_amdgcn_mfma_f32_16x16x32_f16(ah[i], bl[j], acc[i][j], 0, 0, 0);
          acc[i][j] = __builtin_amdgcn_mfma_f32_16x16x32_f16(al[i], bh[j], acc[i][j], 0, 0, 0);
        }
    }
  }
#pragma unroll
  for (int j = 0; j < 4; ++j) {
    int n = wn + j * 16 + col;
    float bb = bias[n];
#pragma unroll
    for (int i = 0; i < 4; ++i) {
      int rbase = row0 + wm + i * 16 + quad * 4;
#pragma unroll
      for (int r = 0; r < 4; ++r) {
        int row = rbase + r;
        if (row < SS)
          out[((size_t)b * SS + row) * HD + n] = tanhf(acc[i][j][r] + bb);
      }
    }
  }
}

// ---------------- SAGPool: score, top-k select, padded write ----------------
__global__ __launch_bounds__(256) void k_sag(
    const float* __restrict__ z, const float* __restrict__ A,
    const float* __restrict__ w1, const float* __restrict__ w2,
    const float* __restrict__ sb, float* __restrict__ xc, int layer) {
  const int b = blockIdx.x, t = threadIdx.x;
  __shared__ float w1s[HD], w2s[HD];
  __shared__ float zw1[SS], sc[SS], fac[SS];
  if (t < HD) { w1s[t] = w1[t]; w2s[t] = w2[t]; }
  __syncthreads();
  float a2 = 0.f;
  if (t < SS) {
    const float4* zr = reinterpret_cast<const float4*>(&z[((size_t)b * SS + t) * HD]);
    float a1 = 0.f;
#pragma unroll
    for (int q = 0; q < HD / 4; ++q) {
      float4 v = zr[q];
      a1 += v.x * w1s[4 * q] + v.y * w1s[4 * q + 1] + v.z * w1s[4 * q + 2] + v.w * w1s[4 * q + 3];
      a2 += v.x * w2s[4 * q] + v.y * w2s[4 * q + 1] + v.z * w2s[4 * q + 2] + v.w * w2s[4 * q + 3];
    }
    zw1[t] = a1;
  }
  __syncthreads();
  if (t < SS) {
    float s = sb[0] + a2;
    const float4* ar = reinterpret_cast<const float4*>(&A[((size_t)b * SS + t) * SS]);
#pragma unroll 5
    for (int q = 0; q < SS / 4; ++q) {
      float4 v = ar[q];
      s += v.x * zw1[4 * q] + v.y * zw1[4 * q + 1] + v.z * zw1[4 * q + 2] + v.w * zw1[4 * q + 3];
    }
    sc[t] = s;
  }
  __syncthreads();
  if (t < SS) {
    float si = sc[t];
    int cnt = 0;
    for (int j = 0; j < SS; ++j) {
      float sj = sc[j];
      cnt += (sj > si || (sj == si && j < t)) ? 1 : 0;
    }
    fac[t] = (cnt < TOPK) ? tanhf(si) : 0.f;
  }
  __syncthreads();
  for (int idx = t; idx < SS * HD; idx += 256) {
    int row = idx >> 7, c = idx & 127;
    xc[((size_t)b * SS + row) * EMB_ + layer * HD + c] =
        fac[row] * z[((size_t)b * SS + row) * HD + c];
  }
}

// ------------- k_proj (MFMA fp16): QK[N,1024] = xc @ [Wq|Wk]^T + b ----------
// XCD-bijective swizzle: each XCD owns 50 contiguous bm-tiles; each tile's 8
// bn-blocks land on the SAME XCD's L2 (A-tile fetched once per XCD).
__global__ __launch_bounds__(256) void k_proj(
    const float* __restrict__ xc, const float* __restrict__ Win,
    const float* __restrict__ bin, __half* __restrict__ QKh) {
  const int wg = (blockIdx.x & 7) * 400 + (blockIdx.x >> 3);
  const int bm = wg >> 3;                // 0..399
  const int bn = wg & 7;                 // 0..7
  const int m0 = bm * 128, n0 = bn * 128;
  const int t    = threadIdx.x;
  const int wave = t >> 6, lane = t & 63;
  const int col  = lane & 15, quad = lane >> 4;
  const int wm = (wave & 1) * 64;        // wave row offset in tile
  const int wn = (wave >> 1) * 64;       // wave col offset in tile
  __shared__ __align__(16) _Float16 As[128][72];   // [m][k], 2-way-free banks
  __shared__ __align__(16) _Float16 Bs[128][72];   // [n][k]
  floatx4 acc[4][4] = {};
  const int lr = t >> 1;                 // staging row 0..127
  const int lk = (t & 1) * 32;           // staging k offset 0/32

  for (int k0 = 0; k0 < EMB_; k0 += 64) {
    __syncthreads();
    const float4* ga = reinterpret_cast<const float4*>(&xc [(size_t)(m0 + lr) * EMB_ + k0 + lk]);
    const float4* gb = reinterpret_cast<const float4*>(&Win[(size_t)(n0 + lr) * EMB_ + k0 + lk]);
#pragma unroll
    for (int q = 0; q < 8; ++q) {
      float4 va = ga[q];
      half4v ha = {(_Float16)va.x, (_Float16)va.y, (_Float16)va.z, (_Float16)va.w};
      *reinterpret_cast<half4v*>(&As[lr][lk + q * 4]) = ha;
      float4 vb = gb[q];
      half4v hb = {(_Float16)vb.x, (_Float16)vb.y, (_Float16)vb.z, (_Float16)vb.w};
      *reinterpret_cast<half4v*>(&Bs[lr][lk + q * 4]) = hb;
    }
    __syncthreads();
#pragma unroll
    for (int ks = 0; ks < 2; ++ks) {
      half8 af[4], bf[4];
#pragma unroll
      for (int i = 0; i < 4; ++i)
        af[i] = *reinterpret_cast<const half8*>(&As[wm + i * 16 + col][ks * 32 + quad * 8]);
#pragma unroll
      for (int j = 0; j < 4; ++j)
        bf[j] = *reinterpret_cast<const half8*>(&Bs[wn + j * 16 + col][ks * 32 + quad * 8]);
#pragma unroll
      for (int i = 0; i < 4; ++i)
#pragma unroll
        for (int j = 0; j < 4; ++j)
          acc[i][j] = __builtin_amdgcn_mfma_f32_16x16x32_f16(af[i], bf[j], acc[i][j], 0, 0, 0);
    }
  }
  // epilogue: C/D layout col=lane&15, row=quad*4+reg
#pragma unroll
  for (int j = 0; j < 4; ++j) {
    int c = n0 + wn + j * 16 + col;
    float bb = bin[c];
#pragma unroll
    for (int i = 0; i < 4; ++i) {
      int rbase = m0 + wm + i * 16 + quad * 4;
#pragma unroll
      for (int r = 0; r < 4; ++r)
        QKh[(size_t)(rbase + r) * 1024 + c] = __float2half(acc[i][j][r] + bb);
    }
  }
}

// ------------- k_attn (MFMA): block = (graph, 16-row tile) ------------------
__global__ __launch_bounds__(256) void k_attn(
    const __half* __restrict__ QKh,
    float* __restrict__ cpbuf,          // [B][8][200], pre-zeroed
    float* __restrict__ attn) {         // [B][200][200]
  const int b  = blockIdx.x / 13;
  const int it = blockIdx.x % 13;
  const int i0 = it * 16;
  const int rows = (SS - i0 >= 16) ? 16 : (SS - i0);   // 16 or 8
  const int t    = threadIdx.x;
  const int wave = t >> 6;
  const int lane = t & 63;
  const int col  = lane & 15;
  const int quad = lane >> 4;

  __shared__ __align__(16) _Float16 kS[208][72];
  __shared__ __align__(16) _Float16 qS[16][72];
  __shared__ __align__(16) float    Ss[16][212];

  float am[13];
  int   soff[13];
  int   kmax = 0;
#pragma unroll
  for (int k = 0; k < 13; ++k) {
    int idx = t + (k << 8);
    am[k] = 0.f;
    if (idx < rows * 200) {
      int i = idx / 200;
      soff[k] = idx + 12 * i;
      kmax = k + 1;
    } else soff[k] = 0;
  }

  const size_t gbase = (size_t)b * SS * 1024;

  for (int h = 0; h < NHD; ++h) {
    __syncthreads();
#pragma unroll
    for (int p = 0; p < 7; ++p) {
      int li = t + (p << 8);
      if (li < 1664) {
        int j = li >> 3, c = li & 7;
        float4 v = {0.f, 0.f, 0.f, 0.f};
        if (j < SS) v = *reinterpret_cast<const float4*>(
            &QKh[gbase + (size_t)j * 1024 + 512 + h * 64 + c * 8]);
        *reinterpret_cast<float4*>(&kS[j][c * 8]) = v;
      }
    }
    if (t < 128) {
      int i = t >> 3, c = t & 7;
      int gi = i0 + i;
      float4 v = {0.f, 0.f, 0.f, 0.f};
      if (gi < SS) v = *reinterpret_cast<const float4*>(
          &QKh[gbase + (size_t)gi * 1024 + h * 64 + c * 8]);
      *reinterpret_cast<float4*>(&qS[i][c * 8]) = v;
    }
    __syncthreads();
    half8 a0 = *reinterpret_cast<const half8*>(&qS[col][quad * 8]);
    half8 a1 = *reinterpret_cast<const half8*>(&qS[col][32 + quad * 8]);
#pragma unroll
    for (int m = 0; m < 4; ++m) {
      int jt = wave + m * 4;
      if (jt < 13) {
        const int j0 = jt * 16;
        half8 b0 = *reinterpret_cast<const half8*>(&kS[j0 + col][quad * 8]);
        half8 b1 = *reinterpret_cast<const half8*>(&kS[j0 + col][32 + quad * 8]);
        floatx4 acc = {0.f, 0.f, 0.f, 0.f};
        acc = __builtin_amdgcn_mfma_f32_16x16x32_f16(a0, b0, acc, 0, 0, 0);
        acc = __builtin_amdgcn_mfma_f32_16x16x32_f16(a1, b1, acc, 0, 0, 0);
#pragma unroll
        for (int r = 0; r < 4; ++r)
          Ss[quad * 4 + r][j0 + col] = acc[r] * 0.125f;
      }
    }
    __syncthreads();
#pragma unroll
    for (int ri = 0; ri < 4; ++ri) {
      int r = wave * 4 + ri;
      if (r < rows) {
        float* srow = &Ss[r][0];
        float s0 = srow[lane], s1 = srow[lane + 64], s2 = srow[lane + 128];
        float s3 = (lane < 8) ? srow[lane + 192] : -1e30f;
        float mx = fmaxf(fmaxf(s0, s1), fmaxf(s2, s3));
#pragma unroll
        for (int o = 32; o; o >>= 1) mx = fmaxf(mx, __shfl_xor(mx, o));
        float e0 = __expf(s0 - mx), e1 = __expf(s1 - mx), e2 = __expf(s2 - mx);
        float e3 = (lane < 8) ? __expf(s3 - mx) : 0.f;
        float sum = e0 + e1 + e2 + e3;
#pragma unroll
        for (int o = 32; o; o >>= 1) sum += __shfl_xor(sum, o);
        float rl = 1.0f / sum;
        srow[lane] = e0 * rl; srow[lane + 64] = e1 * rl; srow[lane + 128] = e2 * rl;
        if (lane < 8) srow[lane + 192] = e3 * rl;
      }
    }
    __syncthreads();
    const float* sflat = &Ss[0][0];
#pragma unroll
    for (int k = 0; k < 13; ++k)
      if (k < kmax) am[k] += sflat[soff[k]] * 0.125f;
    if (t < SS) {
      float s = 0.f;
      for (int i = 0; i < rows; ++i) s += Ss[i][t];
      atomicAdd(&cpbuf[((size_t)b * NHD + h) * SS + t], s);
    }
  }
  float* abase = &attn[((size_t)b * SS + i0) * SS];
#pragma unroll
  for (int k = 0; k < 13; ++k)
    if (k < kmax) abase[t + (k << 8)] = am[k];
}

// ------------- k_pool: tvec_h = cp_h^T @ xc ; pooled = Wv tvec + bv*200 -----
__global__ __launch_bounds__(256) void k_pool(
    const float* __restrict__ xc, const float* __restrict__ cpbuf,
    const float* __restrict__ Win, const float* __restrict__ bin,
    float* __restrict__ pooled) {
  const int b = blockIdx.x, t = threadIdx.x;
  __shared__ float cps[NHD][SS];
  __shared__ float tvs[NHD][EMB_];
  for (int idx = t; idx < NHD * SS; idx += 256) {
    int h = idx / SS, j = idx - h * SS;
    cps[h][j] = cpbuf[((size_t)b * NHD + h) * SS + j];
  }
  __syncthreads();
  const float* xcb = xc + (size_t)b * SS * EMB_;
  float a0[NHD] = {0.f}, a1[NHD] = {0.f};
  for (int j = 0; j < SS; ++j) {
    float x0 = xcb[(size_t)j * EMB_ + t];
    float x1 = xcb[(size_t)j * EMB_ + t + 256];
#pragma unroll
    for (int h = 0; h < NHD; ++h) {
      float c = cps[h][j];
      a0[h] += c * x0; a1[h] += c * x1;
    }
  }
#pragma unroll
  for (int h = 0; h < NHD; ++h) { tvs[h][t] = a0[h]; tvs[h][t + 256] = a1[h]; }
  __syncthreads();
  const int wv = t >> 6, lane = t & 63;
  for (int e = wv; e < EMB_; e += 4) {
    int h = e >> 6;
    const float* wr = Win + (size_t)(2 * EMB_ + e) * EMB_;
    float s = 0.f;
#pragma unroll
    for (int q = 0; q < 8; ++q) s += wr[lane + q * 64] * tvs[h][lane + q * 64];
#pragma unroll
    for (int o = 32; o; o >>= 1) s += __shfl_xor(s, o);
    if (lane == 0) pooled[(size_t)b * EMB_ + e] = bin[2 * EMB_ + e] * (float)SS + s;
  }
}

// ---------------- readout ----------------
__global__ __launch_bounds__(256) void k_final(
    const float* __restrict__ pooled, const float* __restrict__ Wout,
    const float* __restrict__ bout, const float* __restrict__ finw,
    const float* __restrict__ finb, float* __restrict__ out) {
  const int b = blockIdx.x, t = threadIdx.x;
  __shared__ float pl[EMB_], po[EMB_];
  for (int k = t; k < EMB_; k += 256) pl[k] = pooled[(size_t)b * EMB_ + k] * (1.0f / (float)SS);
  __syncthreads();
  for (int e = t; e < EMB_; e += 256) {
    const float* wr = &Wout[(size_t)e * EMB_];
    float a = bout[e];
    for (int k = 0; k < EMB_; ++k) a += wr[k] * pl[k];
    po[e] = a;
  }
  __syncthreads();
  if (t < HD) {
    float a = finb[t];
    for (int e = 0; e < EMB_; ++e) a += po[e] * finw[(size_t)e * HD + t];
    out[(size_t)b * HD + t] = tanhf(a);
  }
}

// ---------------------------------------------------------------------------
extern "C" void kernel_launch(void* const* d_in, const int* in_sizes, int n_in,
                              void* d_out, int out_size, void* d_ws, size_t ws_size,
                              hipStream_t stream) {
  const float* x         = (const float*)d_in[0];
  const int*   ei        = (const int*)d_in[1];
  const float* gcn_w0    = (const float*)d_in[4];
  const float* gcn_w     = (const float*)d_in[5];
  const float* gcn_b     = (const float*)d_in[6];
  const float* lin1_w0   = (const float*)d_in[7];
  const float* lin1_w    = (const float*)d_in[8];
  const float* lin1_b    = (const float*)d_in[9];
  const float* lin2_w    = (const float*)d_in[10];
  const float* lin2_b    = (const float*)d_in[11];
  const float* sag_w1    = (const float*)d_in[12];
  const float* sag_w2    = (const float*)d_in[13];
  const float* sag_b     = (const float*)d_in[14];
  const float* mha_in_w  = (const float*)d_in[15];
  const float* mha_in_b  = (const float*)d_in[16];
  const float* mha_out_w = (const float*)d_in[17];
  const float* mha_out_b = (const float*)d_in[18];
  const float* fin_w     = (const float*)d_in[19];
  const float* fin_b     = (const float*)d_in[20];

  float* ws     = (float*)d_ws;
  float* dinv   = ws;                                  // 51,200
  float* Araw   = dinv + NT;                           // 10,240,000
  float* buf0   = Araw + (size_t)GB * SS * SS;         // 6,553,600
  float* buf1   = buf0 + (size_t)NT * HD;              // 6,553,600
  float* zbuf   = buf1 + (size_t)NT * HD;              // 6,553,600
  float* xcbuf  = zbuf + (size_t)NT * HD;              // 26,214,400 (xc)
  float* pooled = xcbuf + (size_t)NT * EMB_;           // 131,072
  // QK (fp16) overlays [Araw .. zbuf-tail) once the GCN layers are done:
  __half* QKh  = (__half*)Araw;                        // 52,428,800 halves
  float* cpbuf = Araw + 26214400;                      // 409,600 floats (tail of overlay)

  float* outp = (float*)d_out;                         // [B,128]
  float* attn = outp + (size_t)GB * HD;                // [B,200,200]

  // transposed + hi/lo-split weights live in the attn region of d_out
  // (scratch only during the GCN layers; k_attn fully overwrites it later).
  __half* whi = (__half*)attn;                         // 294,912 halves
  __half* wlo = whi + 294912;                          // 294,912 halves

  hipMemsetAsync(Araw, 0, (size_t)GB * SS * SS * sizeof(float), stream);

  k_prep_all<<<12 * 128, 256, 0, stream>>>(gcn_w0, gcn_w, lin1_w0, lin1_w, lin2_w, whi, wlo);
  k_build_A<<<NE_ / 256, 256, 0, stream>>>(ei, ei + NE_, Araw);
  k_dinv<<<NT / 4, 256, 0, stream>>>(Araw, dinv);

  static const int KPg[4]  = {256, 128, 128, 128};
  static const int KP1[4]  = {384, 256, 256, 256};
  static const int OFFg[4] = {0, 98304, 163840, 229376};
  static const int OFF1[4] = {32768, 114688, 180224, 245760};
  static const int OFF2[4] = {81920, 147456, 212992, 278528};

  for (int l = 0; l < NLAY; ++l) {
    const float* zin = (l == 0) ? x : zbuf;
    int k1 = (l == 0) ? KIN : HD;
    // xw = zin @ gcn_w          (no bias, no tanh)
    k_node_mfma<<<NT / 64, 256, 0, stream>>>(zin, k1, nullptr,
                                             whi + OFFg[l], wlo + OFFg[l], KPg[l],
                                             nullptr, buf0, 0);
    // x1 = tanh( Ahat @ xw + b )
    k_agg_mfma<<<GB * 2, 256, 0, stream>>>(Araw, dinv, buf0, gcn_b + l * HD, buf1);
    // h = tanh( [zin|x1] @ l1w + b )
    k_node_mfma<<<NT / 64, 256, 0, stream>>>(zin, k1, buf1,
                                             whi + OFF1[l], wlo + OFF1[l], KP1[l],
                                             lin1_b + l * HD, buf0, 1);
    // z = tanh( h @ l2w + b )
    k_node_mfma<<<NT / 64, 256, 0, stream>>>(buf0, HD, nullptr,
                                             whi + OFF2[l], wlo + OFF2[l], HD,
                                             lin2_b + l * HD, zbuf, 1);
    k_sag<<<GB, 256, 0, stream>>>(zbuf, Araw, sag_w1, sag_w2, sag_b, xcbuf, l);
  }

  // ---- MHA ----
  hipMemsetAsync(cpbuf, 0, (size_t)GB * NHD * SS * sizeof(float), stream);
  k_proj<<<(NT / 128) * 8, 256, 0, stream>>>(xcbuf, mha_in_w, mha_in_b, QKh);
  k_attn<<<GB * 13, 256, 0, stream>>>(QKh, cpbuf, attn);
  k_pool<<<GB, 256, 0, stream>>>(xcbuf, cpbuf, mha_in_w, mha_in_b, pooled);
  k_final<<<GB, 256, 0, stream>>>(pooled, mha_out_w, mha_out_b, fin_w, fin_b, outp);
}

// Round 3
// 1575.255 us; speedup vs baseline: 1.9951x; 1.0308x over previous
//
#include <hip/hip_runtime.h>
#include <hip/hip_fp16.h>

// ---------------------------------------------------------------------------
// GraphConv_8847632629923 : round 8
//   Post-mortem r7: k_proj swizzle cut FETCH 422->85MB but time unchanged ->
//   staging-chain bound, not HBM. In k_proj/k_attn every LDS fragment is
//   consumed ONCE -> LDS roundtrip is pure overhead.
//   - xc now stored as fp16 hi/lo pair (same footprint as fp32 xcbuf);
//     k_proj reads hi (bitwise-identical to staging-time cvt), k_pool
//     reconstructs hi+lo (fp32-equivalent).
//   - k_proj: LDS-free, zero-barrier; A/B fragments direct from L2
//     (Win pre-converted to fp16 once). Predict 250 -> ~100 us.
//   - k_attn: direct fragment loads (no kS/qS staging), LDS 45.8->13.6KB,
//     3 barriers/head, bijective XCD swizzle for QKh L2 locality.
//   GCN-phase kernels unchanged from round 7.
// ---------------------------------------------------------------------------

#define GB   256          // batch (graphs)
#define SS   200          // nodes per graph
#define KIN  200          // input features
#define HD   128          // hidden
#define NLAY 4
#define NHD  8
#define TOPK 100
#define NT   (GB * SS)    // 51200 nodes
#define EPG_ 6400
#define NE_  (GB * EPG_)  // 1,638,400 edges
#define EMB_ 512

typedef _Float16 half8 __attribute__((ext_vector_type(8)));
typedef _Float16 half4v __attribute__((ext_vector_type(4)));
typedef float floatx4 __attribute__((ext_vector_type(4)));

// ---------------- adjacency build ----------------
__global__ __launch_bounds__(256) void k_build_A(const int* __restrict__ src,
                                                 const int* __restrict__ dst,
                                                 float* __restrict__ A) {
  int e = blockIdx.x * 256 + threadIdx.x;
  if (e >= NE_) return;
  int d = dst[e], s = src[e];
  int b = d / SS;
  int dl = d - b * SS;
  int sl = s - b * SS;
  atomicAdd(&A[((size_t)b * SS + dl) * SS + sl], 1.0f);
}

// ---------------- dinv = rsqrt(in_deg + 1) ----------------
__global__ __launch_bounds__(256) void k_dinv(const float* __restrict__ A,
                                              float* __restrict__ dinv) {
  int node = blockIdx.x * 4 + (threadIdx.x >> 6);
  int lane = threadIdx.x & 63;
  const float* r = A + (size_t)node * SS;
  float v = r[lane] + r[lane + 64] + r[lane + 128];
  if (lane < 8) v += r[lane + 192];
#pragma unroll
  for (int o = 32; o; o >>= 1) v += __shfl_xor(v, o);
  if (lane == 0) dinv[node] = rsqrtf(v + 1.0f);
}

// ---------------- weight prep: transpose + fp16 hi/lo split -----------------
__global__ __launch_bounds__(256) void k_prep_all(
    const float* __restrict__ gcn_w0, const float* __restrict__ gcn_w,
    const float* __restrict__ lin1_w0, const float* __restrict__ lin1_w,
    const float* __restrict__ lin2_w,
    __half* __restrict__ whi, __half* __restrict__ wlo) {
  const int mat = blockIdx.x >> 7;   // 0..11
  const int n   = blockIdx.x & 127;
  const int l = mat / 3, which = mat % 3;
  const float* src;
  int K, Kpad;
  if (which == 0) {
    K = l ? HD : KIN;  Kpad = l ? 128 : 256;
    src = l ? gcn_w + (size_t)(l - 1) * HD * HD : gcn_w0;
  } else if (which == 1) {
    K = l ? 2 * HD : KIN + HD;  Kpad = l ? 256 : 384;
    src = l ? lin1_w + (size_t)(l - 1) * 2 * HD * HD : lin1_w0;
  } else {
    K = HD;  Kpad = HD;
    src = lin2_w + (size_t)l * HD * HD;
  }
  int off = (l == 0) ? (which == 0 ? 0 : (which == 1 ? 32768 : 81920))
                     : 98304 + (l - 1) * 65536 +
                       (which == 0 ? 0 : (which == 1 ? 16384 : 49152));
  _Float16* wh = (_Float16*)whi + (size_t)off + (size_t)n * Kpad;
  _Float16* wl = (_Float16*)wlo + (size_t)off + (size_t)n * Kpad;
  for (int k = threadIdx.x; k < Kpad; k += 256) {
    float v = (k < K) ? src[(size_t)k * HD + n] : 0.f;
    _Float16 h = (_Float16)v;
    wh[k] = h;
    wl[k] = (_Float16)(v - (float)h);
  }
}

// ---------------- Win (first 1024 rows of mha_in_w) -> fp16 -----------------
__global__ __launch_bounds__(256) void k_prep_w16(const float* __restrict__ W,
                                                  __half* __restrict__ W16) {
  int i = blockIdx.x * 256 + threadIdx.x;     // over 131072 float4s
  float4 v = reinterpret_cast<const float4*>(W)[i];
  half4v h = {(_Float16)v.x, (_Float16)v.y, (_Float16)v.z, (_Float16)v.w};
  *reinterpret_cast<half4v*>((_Float16*)W16 + (size_t)i * 4) = h;
}

// ------- node GEMM (MFMA split-fp16): out[N,128] = act([in1|in2]@W + b) -----
__global__ __launch_bounds__(256) void k_node_mfma(
    const float* __restrict__ in1, int k1,
    const float* __restrict__ in2,                 // stride HD, may be null
    const __half* __restrict__ Whi, const __half* __restrict__ Wlo,
    int Kpad,
    const float* __restrict__ bias,                // may be null
    float* __restrict__ out, int doTanh) {
  const int m0 = blockIdx.x * 64;
  const int t = threadIdx.x;
  const int wave = t >> 6, lane = t & 63;
  const int col = lane & 15, quad = lane >> 4;
  const int wm = (wave & 1) * 32;
  const int wn = (wave >> 1) * 64;
  __shared__ __align__(16) _Float16 Ah[64][72];
  __shared__ __align__(16) _Float16 Al[64][72];
  floatx4 acc[2][4] = {};
  const int lr = t >> 2;              // staging row 0..63
  const int lk = (t & 3) * 16;        // staging k offset
  const _Float16* Wh = (const _Float16*)Whi;
  const _Float16* Wl = (const _Float16*)Wlo;

  for (int k0 = 0; k0 < Kpad; k0 += 64) {
    __syncthreads();
#pragma unroll
    for (int q = 0; q < 4; ++q) {
      int kg = k0 + lk + q * 4;
      float4 v = {0.f, 0.f, 0.f, 0.f};
      if (kg < k1)
        v = *reinterpret_cast<const float4*>(&in1[(size_t)(m0 + lr) * k1 + kg]);
      else if (in2 && kg < k1 + HD)
        v = *reinterpret_cast<const float4*>(&in2[(size_t)(m0 + lr) * HD + (kg - k1)]);
      half4v h = {(_Float16)v.x, (_Float16)v.y, (_Float16)v.z, (_Float16)v.w};
      half4v lo = {(_Float16)(v.x - (float)h.x), (_Float16)(v.y - (float)h.y),
                   (_Float16)(v.z - (float)h.z), (_Float16)(v.w - (float)h.w)};
      *reinterpret_cast<half4v*>(&Ah[lr][lk + q * 4]) = h;
      *reinterpret_cast<half4v*>(&Al[lr][lk + q * 4]) = lo;
    }
    __syncthreads();
#pragma unroll
    for (int ks = 0; ks < 2; ++ks) {
      half8 ah[2], al[2], bh[4], bl[4];
#pragma unroll
      for (int i = 0; i < 2; ++i) {
        ah[i] = *reinterpret_cast<const half8*>(&Ah[wm + i * 16 + col][ks * 32 + quad * 8]);
        al[i] = *reinterpret_cast<const half8*>(&Al[wm + i * 16 + col][ks * 32 + quad * 8]);
      }
#pragma unroll
      for (int j = 0; j < 4; ++j) {
        const size_t wo = (size_t)(wn + j * 16 + col) * Kpad + k0 + ks * 32 + quad * 8;
        bh[j] = *reinterpret_cast<const half8*>(Wh + wo);
        bl[j] = *reinterpret_cast<const half8*>(Wl + wo);
      }
#pragma unroll
      for (int i = 0; i < 2; ++i)
#pragma unroll
        for (int j = 0; j < 4; ++j) {
          acc[i][j] = __builtin_amdgcn_mfma_f32_16x16x32_f16(ah[i], bh[j], acc[i][j], 0, 0, 0);
          acc[i][j] = __builtin_amdgcn_mfma_f32_16x16x32_f16(ah[i], bl[j], acc[i][j], 0, 0, 0);
          acc[i][j] = __builtin_amdgcn_mfma_f32_16x16x32_f16(al[i], bh[j], acc[i][j], 0, 0, 0);
        }
    }
  }
#pragma unroll
  for (int j = 0; j < 4; ++j) {
    int n = wn + j * 16 + col;
    float bb = bias ? bias[n] : 0.f;
#pragma unroll
    for (int i = 0; i < 2; ++i) {
      int rbase = m0 + wm + i * 16 + quad * 4;
#pragma unroll
      for (int r = 0; r < 4; ++r) {
        float v = acc[i][j][r] + bb;
        if (doTanh) v = tanhf(v);
        out[(size_t)(rbase + r) * HD + n] = v;
      }
    }
  }
}

// ------- GCN aggregation (MFMA split-fp16): x1 = tanh( Ahat @ xw + b ) ------
__global__ __launch_bounds__(256) void k_agg_mfma(
    const float* __restrict__ A, const float* __restrict__ dinv,
    const float* __restrict__ xw, const float* __restrict__ bias,
    float* __restrict__ out) {
  const int b    = blockIdx.x >> 1;
  const int row0 = (blockIdx.x & 1) * 128;
  const int t = threadIdx.x;
  const int wave = t >> 6, lane = t & 63;
  const int col = lane & 15, quad = lane >> 4;
  const int wm = (wave & 1) * 64, wn = (wave >> 1) * 64;
  __shared__ __align__(16) _Float16 Ah[128][72];
  __shared__ __align__(16) _Float16 Al[128][72];
  __shared__ __align__(16) _Float16 Bh[128][72];
  __shared__ __align__(16) _Float16 Bl[128][72];
  __shared__ float dvs[256];
  dvs[t] = (t < SS) ? dinv[b * SS + t] : 0.f;
  floatx4 acc[4][4] = {};
  const float* Ab  = A  + (size_t)b * SS * SS;
  const float* xwb = xw + (size_t)b * SS * HD;
  const int lr = t >> 1, lk = (t & 1) * 32;
  const int d = row0 + lr;
  __syncthreads();
  const float dvd = (d < SS) ? dvs[d] : 0.f;

  for (int k0 = 0; k0 < 256; k0 += 64) {
    __syncthreads();
    // ---- stage Ahat rows (hi/lo) ----
#pragma unroll
    for (int q = 0; q < 8; ++q) {
      int s = k0 + lk + q * 4;
      float4 v = {0.f, 0.f, 0.f, 0.f};
      if (d < SS && s < SS)
        v = *reinterpret_cast<const float4*>(&Ab[(size_t)d * SS + s]);
      float e0 = (v.x + ((s + 0 == d) ? 1.f : 0.f)) * dvd * dvs[(s + 0) & 255];
      float e1 = (v.y + ((s + 1 == d) ? 1.f : 0.f)) * dvd * dvs[(s + 1) & 255];
      float e2 = (v.z + ((s + 2 == d) ? 1.f : 0.f)) * dvd * dvs[(s + 2) & 255];
      float e3 = (v.w + ((s + 3 == d) ? 1.f : 0.f)) * dvd * dvs[(s + 3) & 255];
      half4v h = {(_Float16)e0, (_Float16)e1, (_Float16)e2, (_Float16)e3};
      half4v lo = {(_Float16)(e0 - (float)h.x), (_Float16)(e1 - (float)h.y),
                   (_Float16)(e2 - (float)h.z), (_Float16)(e3 - (float)h.w)};
      *reinterpret_cast<half4v*>(&Ah[lr][lk + q * 4]) = h;
      *reinterpret_cast<half4v*>(&Al[lr][lk + q * 4]) = lo;
    }
    // ---- stage xw transposed (hi/lo), XOR-swizzled ----
#pragma unroll
    for (int p = 0; p < 8; ++p) {
      int idx = t + p * 256;
      int c4 = idx & 31, ss = idx >> 5;          // ss 0..63
      int s = k0 + ss;
      float4 v = {0.f, 0.f, 0.f, 0.f};
      if (s < SS)
        v = *reinterpret_cast<const float4*>(&xwb[(size_t)s * HD + c4 * 4]);
      int ssx = ss ^ ((c4 & 7) << 3);            // (n>>2)&7 == c4&7 for n=4*c4+j
      float e[4] = {v.x, v.y, v.z, v.w};
#pragma unroll
      for (int j = 0; j < 4; ++j) {
        _Float16 h = (_Float16)e[j];
        Bh[c4 * 4 + j][ssx] = h;
        Bl[c4 * 4 + j][ssx] = (_Float16)(e[j] - (float)h);
      }
    }
    __syncthreads();
#pragma unroll
    for (int ks = 0; ks < 2; ++ks) {
      half8 ah[4], al[4], bh[4], bl[4];
#pragma unroll
      for (int i = 0; i < 4; ++i) {
        ah[i] = *reinterpret_cast<const half8*>(&Ah[wm + i * 16 + col][ks * 32 + quad * 8]);
        al[i] = *reinterpret_cast<const half8*>(&Al[wm + i * 16 + col][ks * 32 + quad * 8]);
      }
#pragma unroll
      for (int j = 0; j < 4; ++j) {
        int n = wn + j * 16 + col;
        int koff = (ks * 32 + quad * 8) ^ (((n >> 2) & 7) << 3);
        bh[j] = *reinterpret_cast<const half8*>(&Bh[n][koff]);
        bl[j] = *reinterpret_cast<const half8*>(&Bl[n][koff]);
      }
#pragma unroll
      for (int i = 0; i < 4; ++i)
#pragma unroll
        for (int j = 0; j < 4; ++j) {
          acc[i][j] = __builtin_amdgcn_mfma_f32_16x16x32_f16(ah[i], bh[j], acc[i][j], 0, 0, 0);
          acc[i][j] = __builtin_amdgcn_mfma_f32_16x16x32_f16(ah[i], bl[j], acc[i][j], 0, 0, 0);
          acc[i][j] = __builtin_amdgcn_mfma_f32_16x16x32_f16(al[i], bh[j], acc[i][j], 0, 0, 0);
        }
    }
  }
#pragma unroll
  for (int j = 0; j < 4; ++j) {
    int n = wn + j * 16 + col;
    float bb = bias[n];
#pragma unroll
    for (int i = 0; i < 4; ++i) {
      int rbase = row0 + wm + i * 16 + quad * 4;
#pragma unroll
      for (int r = 0; r < 4; ++r) {
        int row = rbase + r;
        if (row < SS)
          out[((size_t)b * SS + row) * HD + n] = tanhf(acc[i][j][r] + bb);
      }
    }
  }
}

// ---------------- SAGPool: score, top-k select, padded write ----------------
// Output xc is stored as an fp16 hi/lo pair (hi feeds k_proj — identical
// rounding to staging-time cvt; hi+lo reconstructs fp32 for k_pool).
__global__ __launch_bounds__(256) void k_sag(
    const float* __restrict__ z, const float* __restrict__ A,
    const float* __restrict__ w1, const float* __restrict__ w2,
    const float* __restrict__ sb,
    __half* __restrict__ xch, __half* __restrict__ xcl, int layer) {
  const int b = blockIdx.x, t = threadIdx.x;
  __shared__ float w1s[HD], w2s[HD];
  __shared__ float zw1[SS], sc[SS], fac[SS];
  if (t < HD) { w1s[t] = w1[t]; w2s[t] = w2[t]; }
  __syncthreads();
  float a2 = 0.f;
  if (t < SS) {
    const float4* zr = reinterpret_cast<const float4*>(&z[((size_t)b * SS + t) * HD]);
    float a1 = 0.f;
#pragma unroll
    for (int q = 0; q < HD / 4; ++q) {
      float4 v = zr[q];
      a1 += v.x * w1s[4 * q] + v.y * w1s[4 * q + 1] + v.z * w1s[4 * q + 2] + v.w * w1s[4 * q + 3];
      a2 += v.x * w2s[4 * q] + v.y * w2s[4 * q + 1] + v.z * w2s[4 * q + 2] + v.w * w2s[4 * q + 3];
    }
    zw1[t] = a1;
  }
  __syncthreads();
  if (t < SS) {
    float s = sb[0] + a2;
    const float4* ar = reinterpret_cast<const float4*>(&A[((size_t)b * SS + t) * SS]);
#pragma unroll 5
    for (int q = 0; q < SS / 4; ++q) {
      float4 v = ar[q];
      s += v.x * zw1[4 * q] + v.y * zw1[4 * q + 1] + v.z * zw1[4 * q + 2] + v.w * zw1[4 * q + 3];
    }
    sc[t] = s;
  }
  __syncthreads();
  if (t < SS) {
    float si = sc[t];
    int cnt = 0;
    for (int j = 0; j < SS; ++j) {
      float sj = sc[j];
      cnt += (sj > si || (sj == si && j < t)) ? 1 : 0;
    }
    fac[t] = (cnt < TOPK) ? tanhf(si) : 0.f;
  }
  __syncthreads();
  _Float16* xh = (_Float16*)xch;
  _Float16* xl = (_Float16*)xcl;
  for (int idx = t; idx < SS * HD; idx += 256) {
    int row = idx >> 7, c = idx & 127;
    float v = fac[row] * z[((size_t)b * SS + row) * HD + c];
    _Float16 h = (_Float16)v;
    size_t o = ((size_t)b * SS + row) * EMB_ + layer * HD + c;
    xh[o] = h;
    xl[o] = (_Float16)(v - (float)h);
  }
}

// ------------- k_proj (MFMA fp16, LDS-free): QK = xc16 @ Win16^T + b --------
// Fragments loaded directly from L2 (each is consumed once — LDS roundtrip
// was pure overhead). Zero barriers. XCD-bijective block swizzle retained.
__global__ __launch_bounds__(256) void k_proj(
    const __half* __restrict__ xch, const __half* __restrict__ Win16,
    const float* __restrict__ bin, __half* __restrict__ QKh) {
  const int wg = (blockIdx.x & 7) * 400 + (blockIdx.x >> 3);
  const int bm = wg >> 3;                // 0..399
  const int bn = wg & 7;                 // 0..7
  const int m0 = bm * 128, n0 = bn * 128;
  const int t = threadIdx.x;
  const int wave = t >> 6, lane = t & 63;
  const int col = lane & 15, quad = lane >> 4;
  const int wm = (wave & 1) * 64;
  const int wn = (wave >> 1) * 64;
  floatx4 acc[4][4] = {};
  const _Float16* X = (const _Float16*)xch;
  const _Float16* W = (const _Float16*)Win16;
  const _Float16* xa[4];
  const _Float16* wb[4];
#pragma unroll
  for (int i = 0; i < 4; ++i)
    xa[i] = X + (size_t)(m0 + wm + i * 16 + col) * EMB_ + quad * 8;
#pragma unroll
  for (int j = 0; j < 4; ++j)
    wb[j] = W + (size_t)(n0 + wn + j * 16 + col) * EMB_ + quad * 8;

#pragma unroll 4
  for (int k0 = 0; k0 < EMB_; k0 += 32) {
    half8 af[4], bf[4];
#pragma unroll
    for (int i = 0; i < 4; ++i) af[i] = *reinterpret_cast<const half8*>(xa[i] + k0);
#pragma unroll
    for (int j = 0; j < 4; ++j) bf[j] = *reinterpret_cast<const half8*>(wb[j] + k0);
#pragma unroll
    for (int i = 0; i < 4; ++i)
#pragma unroll
      for (int j = 0; j < 4; ++j)
        acc[i][j] = __builtin_amdgcn_mfma_f32_16x16x32_f16(af[i], bf[j], acc[i][j], 0, 0, 0);
  }
  // epilogue: C/D layout col=lane&15, row=quad*4+reg
#pragma unroll
  for (int j = 0; j < 4; ++j) {
    int c = n0 + wn + j * 16 + col;
    float bb = bin[c];
#pragma unroll
    for (int i = 0; i < 4; ++i) {
      int rbase = m0 + wm + i * 16 + quad * 4;
#pragma unroll
      for (int r = 0; r < 4; ++r)
        QKh[(size_t)(rbase + r) * 1024 + c] = __float2half(acc[i][j][r] + bb);
    }
  }
}

// ------------- k_attn (MFMA): block = (graph, 16-row tile) ------------------
// Q/K fragments loaded directly from L2 (no LDS staging, 3 barriers/head).
// Rows >= SS read in-bounds garbage (next graph / cpbuf) but those Ss
// rows/cols are never consumed. Bijective XCD swizzle keeps one graph's 13
// row-tiles on one XCD's L2.
__global__ __launch_bounds__(256) void k_attn(
    const __half* __restrict__ QKh,
    float* __restrict__ cpbuf,          // [B][8][200], pre-zeroed
    float* __restrict__ attn) {         // [B][200][200]
  const int bx = (blockIdx.x & 7) * 416 + (blockIdx.x >> 3);   // 3328 = 8*416
  const int b  = bx / 13;
  const int it = bx % 13;
  const int i0 = it * 16;
  const int rows = (SS - i0 >= 16) ? 16 : (SS - i0);   // 16 or 8
  const int t    = threadIdx.x;
  const int wave = t >> 6;
  const int lane = t & 63;
  const int col  = lane & 15;
  const int quad = lane >> 4;

  __shared__ __align__(16) float Ss[16][212];

  float am[13];
  int   soff[13];
  int   kmax = 0;
#pragma unroll
  for (int k = 0; k < 13; ++k) {
    int idx = t + (k << 8);
    am[k] = 0.f;
    if (idx < rows * 200) {
      int i = idx / 200;
      soff[k] = idx + 12 * i;
      kmax = k + 1;
    } else soff[k] = 0;
  }

  const _Float16* Qbase = (const _Float16*)QKh + (size_t)b * SS * 1024;
  const _Float16* qrow = Qbase + (size_t)(i0 + col) * 1024 + quad * 8;
  // K fragment row pointers for this wave's jt set (jt = wave + 4m)
  const _Float16* krow[4];
#pragma unroll
  for (int m = 0; m < 4; ++m) {
    int jt = wave + m * 4;
    krow[m] = Qbase + (size_t)(jt * 16 + col) * 1024 + 512 + quad * 8;
  }

  for (int h = 0; h < NHD; ++h) {
    const int hoff = h * 64;
    half8 a0 = *reinterpret_cast<const half8*>(qrow + hoff);
    half8 a1 = *reinterpret_cast<const half8*>(qrow + hoff + 32);
#pragma unroll
    for (int m = 0; m < 4; ++m) {
      int jt = wave + m * 4;
      if (jt < 13) {
        half8 b0 = *reinterpret_cast<const half8*>(krow[m] + hoff);
        half8 b1 = *reinterpret_cast<const half8*>(krow[m] + hoff + 32);
        floatx4 acc = {0.f, 0.f, 0.f, 0.f};
        acc = __builtin_amdgcn_mfma_f32_16x16x32_f16(a0, b0, acc, 0, 0, 0);
        acc = __builtin_amdgcn_mfma_f32_16x16x32_f16(a1, b1, acc, 0, 0, 0);
#pragma unroll
        for (int r = 0; r < 4; ++r)
          Ss[quad * 4 + r][jt * 16 + col] = acc[r] * 0.125f;
      }
    }
    __syncthreads();
#pragma unroll
    for (int ri = 0; ri < 4; ++ri) {
      int r = wave * 4 + ri;
      if (r < rows) {
        float* srow = &Ss[r][0];
        float s0 = srow[lane], s1 = srow[lane + 64], s2 = srow[lane + 128];
        float s3 = (lane < 8) ? srow[lane + 192] : -1e30f;
        float mx = fmaxf(fmaxf(s0, s1), fmaxf(s2, s3));
#pragma unroll
        for (int o = 32; o; o >>= 1) mx = fmaxf(mx, __shfl_xor(mx, o));
        float e0 = __expf(s0 - mx), e1 = __expf(s1 - mx), e2 = __expf(s2 - mx);
        float e3 = (lane < 8) ? __expf(s3 - mx) : 0.f;
        float sum = e0 + e1 + e2 + e3;
#pragma unroll
        for (int o = 32; o; o >>= 1) sum += __shfl_xor(sum, o);
        float rl = 1.0f / sum;
        srow[lane] = e0 * rl; srow[lane + 64] = e1 * rl; srow[lane + 128] = e2 * rl;
        if (lane < 8) srow[lane + 192] = e3 * rl;
      }
    }
    __syncthreads();
    const float* sflat = &Ss[0][0];
#pragma unroll
    for (int k = 0; k < 13; ++k)
      if (k < kmax) am[k] += sflat[soff[k]] * 0.125f;
    if (t < SS) {
      float s = 0.f;
      for (int i = 0; i < rows; ++i) s += Ss[i][t];
      atomicAdd(&cpbuf[((size_t)b * NHD + h) * SS + t], s);
    }
    __syncthreads();
  }
  float* abase = &attn[((size_t)b * SS + i0) * SS];
#pragma unroll
  for (int k = 0; k < 13; ++k)
    if (k < kmax) abase[t + (k << 8)] = am[k];
}

// ------------- k_pool: tvec_h = cp_h^T @ xc ; pooled = Wv tvec + bv*200 -----
__global__ __launch_bounds__(256) void k_pool(
    const __half* __restrict__ xch, const __half* __restrict__ xcl,
    const float* __restrict__ cpbuf,
    const float* __restrict__ Win, const float* __restrict__ bin,
    float* __restrict__ pooled) {
  const int b = blockIdx.x, t = threadIdx.x;
  __shared__ float cps[NHD][SS];
  __shared__ float tvs[NHD][EMB_];
  for (int idx = t; idx < NHD * SS; idx += 256) {
    int h = idx / SS, j = idx - h * SS;
    cps[h][j] = cpbuf[((size_t)b * NHD + h) * SS + j];
  }
  __syncthreads();
  const _Float16* xh = (const _Float16*)xch + (size_t)b * SS * EMB_;
  const _Float16* xl = (const _Float16*)xcl + (size_t)b * SS * EMB_;
  float a0[NHD] = {0.f}, a1[NHD] = {0.f};
  for (int j = 0; j < SS; ++j) {
    float x0 = (float)xh[(size_t)j * EMB_ + t] + (float)xl[(size_t)j * EMB_ + t];
    float x1 = (float)xh[(size_t)j * EMB_ + t + 256] + (float)xl[(size_t)j * EMB_ + t + 256];
#pragma unroll
    for (int h = 0; h < NHD; ++h) {
      float c = cps[h][j];
      a0[h] += c * x0; a1[h] += c * x1;
    }
  }
#pragma unroll
  for (int h = 0; h < NHD; ++h) { tvs[h][t] = a0[h]; tvs[h][t + 256] = a1[h]; }
  __syncthreads();
  const int wv = t >> 6, lane = t & 63;
  for (int e = wv; e < EMB_; e += 4) {
    int h = e >> 6;
    const float* wr = Win + (size_t)(2 * EMB_ + e) * EMB_;
    float s = 0.f;
#pragma unroll
    for (int q = 0; q < 8; ++q) s += wr[lane + q * 64] * tvs[h][lane + q * 64];
#pragma unroll
    for (int o = 32; o; o >>= 1) s += __shfl_xor(s, o);
    if (lane == 0) pooled[(size_t)b * EMB_ + e] = bin[2 * EMB_ + e] * (float)SS + s;
  }
}

// ---------------- readout ----------------
__global__ __launch_bounds__(256) void k_final(
    const float* __restrict__ pooled, const float* __restrict__ Wout,
    const float* __restrict__ bout, const float* __restrict__ finw,
    const float* __restrict__ finb, float* __restrict__ out) {
  const int b = blockIdx.x, t = threadIdx.x;
  __shared__ float pl[EMB_], po[EMB_];
  for (int k = t; k < EMB_; k += 256) pl[k] = pooled[(size_t)b * EMB_ + k] * (1.0f / (float)SS);
  __syncthreads();
  for (int e = t; e < EMB_; e += 256) {
    const float* wr = &Wout[(size_t)e * EMB_];
    float a = bout[e];
    for (int k = 0; k < EMB_; ++k) a += wr[k] * pl[k];
    po[e] = a;
  }
  __syncthreads();
  if (t < HD) {
    float a = finb[t];
    for (int e = 0; e < EMB_; ++e) a += po[e] * finw[(size_t)e * HD + t];
    out[(size_t)b * HD + t] = tanhf(a);
  }
}

// ---------------------------------------------------------------------------
extern "C" void kernel_launch(void* const* d_in, const int* in_sizes, int n_in,
                              void* d_out, int out_size, void* d_ws, size_t ws_size,
                              hipStream_t stream) {
  const float* x         = (const float*)d_in[0];
  const int*   ei        = (const int*)d_in[1];
  const float* gcn_w0    = (const float*)d_in[4];
  const float* gcn_w     = (const float*)d_in[5];
  const float* gcn_b     = (const float*)d_in[6];
  const float* lin1_w0   = (const float*)d_in[7];
  const float* lin1_w    = (const float*)d_in[8];
  const float* lin1_b    = (const float*)d_in[9];
  const float* lin2_w    = (const float*)d_in[10];
  const float* lin2_b    = (const float*)d_in[11];
  const float* sag_w1    = (const float*)d_in[12];
  const float* sag_w2    = (const float*)d_in[13];
  const float* sag_b     = (const float*)d_in[14];
  const float* mha_in_w  = (const float*)d_in[15];
  const float* mha_in_b  = (const float*)d_in[16];
  const float* mha_out_w = (const float*)d_in[17];
  const float* mha_out_b = (const float*)d_in[18];
  const float* fin_w     = (const float*)d_in[19];
  const float* fin_b     = (const float*)d_in[20];

  float* ws     = (float*)d_ws;
  float* dinv   = ws;                                  // 51,200
  float* Araw   = dinv + NT;                           // 10,240,000
  float* buf0   = Araw + (size_t)GB * SS * SS;         // 6,553,600
  float* buf1   = buf0 + (size_t)NT * HD;              // 6,553,600
  float* zbuf   = buf1 + (size_t)NT * HD;              // 6,553,600
  float* xcf    = zbuf + (size_t)NT * HD;              // 26,214,400-float region
  __half* xch   = (__half*)xcf;                        // [N][512] fp16 hi
  __half* xcl   = xch + (size_t)NT * EMB_;             // [N][512] fp16 lo
  float* pooled = xcf + (size_t)NT * EMB_;             // 131,072
  // QK (fp16) overlays [Araw .. zbuf-tail) once the GCN layers are done:
  __half* QKh  = (__half*)Araw;                        // 52,428,800 halves
  float* cpbuf = Araw + 26214400;                      // 409,600 floats (tail of overlay)

  float* outp = (float*)d_out;                         // [B,128]
  float* attn = outp + (size_t)GB * HD;                // [B,200,200]

  // transposed + hi/lo-split weights + fp16 Win live in the d_out attn region
  // (scratch only until k_attn fully overwrites it).
  __half* whi   = (__half*)attn;                       // 294,912 halves
  __half* wlo   = whi + 294912;                        // 294,912 halves
  __half* Win16 = wlo + 294912;                        // 524,288 halves

  hipMemsetAsync(Araw, 0, (size_t)GB * SS * SS * sizeof(float), stream);

  k_prep_all<<<12 * 128, 256, 0, stream>>>(gcn_w0, gcn_w, lin1_w0, lin1_w, lin2_w, whi, wlo);
  k_prep_w16<<<512, 256, 0, stream>>>(mha_in_w, Win16);
  k_build_A<<<NE_ / 256, 256, 0, stream>>>(ei, ei + NE_, Araw);
  k_dinv<<<NT / 4, 256, 0, stream>>>(Araw, dinv);

  static const int KPg[4]  = {256, 128, 128, 128};
  static const int KP1[4]  = {384, 256, 256, 256};
  static const int OFFg[4] = {0, 98304, 163840, 229376};
  static const int OFF1[4] = {32768, 114688, 180224, 245760};
  static const int OFF2[4] = {81920, 147456, 212992, 278528};

  for (int l = 0; l < NLAY; ++l) {
    const float* zin = (l == 0) ? x : zbuf;
    int k1 = (l == 0) ? KIN : HD;
    // xw = zin @ gcn_w          (no bias, no tanh)
    k_node_mfma<<<NT / 64, 256, 0, stream>>>(zin, k1, nullptr,
                                             whi + OFFg[l], wlo + OFFg[l], KPg[l],
                                             nullptr, buf0, 0);
    // x1 = tanh( Ahat @ xw + b )
    k_agg_mfma<<<GB * 2, 256, 0, stream>>>(Araw, dinv, buf0, gcn_b + l * HD, buf1);
    // h = tanh( [zin|x1] @ l1w + b )
    k_node_mfma<<<NT / 64, 256, 0, stream>>>(zin, k1, buf1,
                                             whi + OFF1[l], wlo + OFF1[l], KP1[l],
                                             lin1_b + l * HD, buf0, 1);
    // z = tanh( h @ l2w + b )
    k_node_mfma<<<NT / 64, 256, 0, stream>>>(buf0, HD, nullptr,
                                             whi + OFF2[l], wlo + OFF2[l], HD,
                                             lin2_b + l * HD, zbuf, 1);
    k_sag<<<GB, 256, 0, stream>>>(zbuf, Araw, sag_w1, sag_w2, sag_b, xch, xcl, l);
  }

  // ---- MHA ----
  hipMemsetAsync(cpbuf, 0, (size_t)GB * NHD * SS * sizeof(float), stream);
  k_proj<<<(NT / 128) * 8, 256, 0, stream>>>(xch, Win16, mha_in_b, QKh);
  k_attn<<<GB * 13, 256, 0, stream>>>(QKh, cpbuf, attn);
  k_pool<<<GB, 256, 0, stream>>>(xch, xcl, cpbuf, mha_in_w, mha_in_b, pooled);
  k_final<<<GB, 256, 0, stream>>>(pooled, mha_out_w, mha_out_b, fin_w, fin_b, outp);
}

// Round 4
// 1450.103 us; speedup vs baseline: 2.1673x; 1.0863x over previous
//
#include <hip/hip_runtime.h>
#include <hip/hip_fp16.h>

// ---------------------------------------------------------------------------
// GraphConv_8847632629923 : round 9
//   Post-mortem r8: LDS-free k_proj is VMEM-latency-bound (MfmaUtil 9.7%,
//   HBM 8%, occupancy 20%) — direct L2 fragment loads feed MFMAs with no
//   latency batching. Fix: m97 structure (verified 874 TF on this chip):
//   global_load_lds width-16 staging of the (already-fp16) xc/Win16 tiles,
//   linear LDS dest + inverse-swizzled global source + swizzled ds_read_b128
//   (rule #21), 2-barrier K-loop, BK=64. Only k_proj changed this round.
// ---------------------------------------------------------------------------

#define GB   256          // batch (graphs)
#define SS   200          // nodes per graph
#define KIN  200          // input features
#define HD   128          // hidden
#define NLAY 4
#define NHD  8
#define TOPK 100
#define NT   (GB * SS)    // 51200 nodes
#define EPG_ 6400
#define NE_  (GB * EPG_)  // 1,638,400 edges
#define EMB_ 512

typedef _Float16 half8 __attribute__((ext_vector_type(8)));
typedef _Float16 half4v __attribute__((ext_vector_type(4)));
typedef float floatx4 __attribute__((ext_vector_type(4)));

// ---------------- adjacency build ----------------
__global__ __launch_bounds__(256) void k_build_A(const int* __restrict__ src,
                                                 const int* __restrict__ dst,
                                                 float* __restrict__ A) {
  int e = blockIdx.x * 256 + threadIdx.x;
  if (e >= NE_) return;
  int d = dst[e], s = src[e];
  int b = d / SS;
  int dl = d - b * SS;
  int sl = s - b * SS;
  atomicAdd(&A[((size_t)b * SS + dl) * SS + sl], 1.0f);
}

// ---------------- dinv = rsqrt(in_deg + 1) ----------------
__global__ __launch_bounds__(256) void k_dinv(const float* __restrict__ A,
                                              float* __restrict__ dinv) {
  int node = blockIdx.x * 4 + (threadIdx.x >> 6);
  int lane = threadIdx.x & 63;
  const float* r = A + (size_t)node * SS;
  float v = r[lane] + r[lane + 64] + r[lane + 128];
  if (lane < 8) v += r[lane + 192];
#pragma unroll
  for (int o = 32; o; o >>= 1) v += __shfl_xor(v, o);
  if (lane == 0) dinv[node] = rsqrtf(v + 1.0f);
}

// ---------------- weight prep: transpose + fp16 hi/lo split -----------------
__global__ __launch_bounds__(256) void k_prep_all(
    const float* __restrict__ gcn_w0, const float* __restrict__ gcn_w,
    const float* __restrict__ lin1_w0, const float* __restrict__ lin1_w,
    const float* __restrict__ lin2_w,
    __half* __restrict__ whi, __half* __restrict__ wlo) {
  const int mat = blockIdx.x >> 7;   // 0..11
  const int n   = blockIdx.x & 127;
  const int l = mat / 3, which = mat % 3;
  const float* src;
  int K, Kpad;
  if (which == 0) {
    K = l ? HD : KIN;  Kpad = l ? 128 : 256;
    src = l ? gcn_w + (size_t)(l - 1) * HD * HD : gcn_w0;
  } else if (which == 1) {
    K = l ? 2 * HD : KIN + HD;  Kpad = l ? 256 : 384;
    src = l ? lin1_w + (size_t)(l - 1) * 2 * HD * HD : lin1_w0;
  } else {
    K = HD;  Kpad = HD;
    src = lin2_w + (size_t)l * HD * HD;
  }
  int off = (l == 0) ? (which == 0 ? 0 : (which == 1 ? 32768 : 81920))
                     : 98304 + (l - 1) * 65536 +
                       (which == 0 ? 0 : (which == 1 ? 16384 : 49152));
  _Float16* wh = (_Float16*)whi + (size_t)off + (size_t)n * Kpad;
  _Float16* wl = (_Float16*)wlo + (size_t)off + (size_t)n * Kpad;
  for (int k = threadIdx.x; k < Kpad; k += 256) {
    float v = (k < K) ? src[(size_t)k * HD + n] : 0.f;
    _Float16 h = (_Float16)v;
    wh[k] = h;
    wl[k] = (_Float16)(v - (float)h);
  }
}

// ---------------- Win (first 1024 rows of mha_in_w) -> fp16 -----------------
__global__ __launch_bounds__(256) void k_prep_w16(const float* __restrict__ W,
                                                  __half* __restrict__ W16) {
  int i = blockIdx.x * 256 + threadIdx.x;     // over 131072 float4s
  float4 v = reinterpret_cast<const float4*>(W)[i];
  half4v h = {(_Float16)v.x, (_Float16)v.y, (_Float16)v.z, (_Float16)v.w};
  *reinterpret_cast<half4v*>((_Float16*)W16 + (size_t)i * 4) = h;
}

// ------- node GEMM (MFMA split-fp16): out[N,128] = act([in1|in2]@W + b) -----
__global__ __launch_bounds__(256) void k_node_mfma(
    const float* __restrict__ in1, int k1,
    const float* __restrict__ in2,                 // stride HD, may be null
    const __half* __restrict__ Whi, const __half* __restrict__ Wlo,
    int Kpad,
    const float* __restrict__ bias,                // may be null
    float* __restrict__ out, int doTanh) {
  const int m0 = blockIdx.x * 64;
  const int t = threadIdx.x;
  const int wave = t >> 6, lane = t & 63;
  const int col = lane & 15, quad = lane >> 4;
  const int wm = (wave & 1) * 32;
  const int wn = (wave >> 1) * 64;
  __shared__ __align__(16) _Float16 Ah[64][72];
  __shared__ __align__(16) _Float16 Al[64][72];
  floatx4 acc[2][4] = {};
  const int lr = t >> 2;              // staging row 0..63
  const int lk = (t & 3) * 16;        // staging k offset
  const _Float16* Wh = (const _Float16*)Whi;
  const _Float16* Wl = (const _Float16*)Wlo;

  for (int k0 = 0; k0 < Kpad; k0 += 64) {
    __syncthreads();
#pragma unroll
    for (int q = 0; q < 4; ++q) {
      int kg = k0 + lk + q * 4;
      float4 v = {0.f, 0.f, 0.f, 0.f};
      if (kg < k1)
        v = *reinterpret_cast<const float4*>(&in1[(size_t)(m0 + lr) * k1 + kg]);
      else if (in2 && kg < k1 + HD)
        v = *reinterpret_cast<const float4*>(&in2[(size_t)(m0 + lr) * HD + (kg - k1)]);
      half4v h = {(_Float16)v.x, (_Float16)v.y, (_Float16)v.z, (_Float16)v.w};
      half4v lo = {(_Float16)(v.x - (float)h.x), (_Float16)(v.y - (float)h.y),
                   (_Float16)(v.z - (float)h.z), (_Float16)(v.w - (float)h.w)};
      *reinterpret_cast<half4v*>(&Ah[lr][lk + q * 4]) = h;
      *reinterpret_cast<half4v*>(&Al[lr][lk + q * 4]) = lo;
    }
    __syncthreads();
#pragma unroll
    for (int ks = 0; ks < 2; ++ks) {
      half8 ah[2], al[2], bh[4], bl[4];
#pragma unroll
      for (int i = 0; i < 2; ++i) {
        ah[i] = *reinterpret_cast<const half8*>(&Ah[wm + i * 16 + col][ks * 32 + quad * 8]);
        al[i] = *reinterpret_cast<const half8*>(&Al[wm + i * 16 + col][ks * 32 + quad * 8]);
      }
#pragma unroll
      for (int j = 0; j < 4; ++j) {
        const size_t wo = (size_t)(wn + j * 16 + col) * Kpad + k0 + ks * 32 + quad * 8;
        bh[j] = *reinterpret_cast<const half8*>(Wh + wo);
        bl[j] = *reinterpret_cast<const half8*>(Wl + wo);
      }
#pragma unroll
      for (int i = 0; i < 2; ++i)
#pragma unroll
        for (int j = 0; j < 4; ++j) {
          acc[i][j] = __builtin_amdgcn_mfma_f32_16x16x32_f16(ah[i], bh[j], acc[i][j], 0, 0, 0);
          acc[i][j] = __builtin_amdgcn_mfma_f32_16x16x32_f16(ah[i], bl[j], acc[i][j], 0, 0, 0);
          acc[i][j] = __builtin_amdgcn_mfma_f32_16x16x32_f16(al[i], bh[j], acc[i][j], 0, 0, 0);
        }
    }
  }
#pragma unroll
  for (int j = 0; j < 4; ++j) {
    int n = wn + j * 16 + col;
    float bb = bias ? bias[n] : 0.f;
#pragma unroll
    for (int i = 0; i < 2; ++i) {
      int rbase = m0 + wm + i * 16 + quad * 4;
#pragma unroll
      for (int r = 0; r < 4; ++r) {
        float v = acc[i][j][r] + bb;
        if (doTanh) v = tanhf(v);
        out[(size_t)(rbase + r) * HD + n] = v;
      }
    }
  }
}

// ------- GCN aggregation (MFMA split-fp16): x1 = tanh( Ahat @ xw + b ) ------
__global__ __launch_bounds__(256) void k_agg_mfma(
    const float* __restrict__ A, const float* __restrict__ dinv,
    const float* __restrict__ xw, const float* __restrict__ bias,
    float* __restrict__ out) {
  const int b    = blockIdx.x >> 1;
  const int row0 = (blockIdx.x & 1) * 128;
  const int t = threadIdx.x;
  const int wave = t >> 6, lane = t & 63;
  const int col = lane & 15, quad = lane >> 4;
  const int wm = (wave & 1) * 64, wn = (wave >> 1) * 64;
  __shared__ __align__(16) _Float16 Ah[128][72];
  __shared__ __align__(16) _Float16 Al[128][72];
  __shared__ __align__(16) _Float16 Bh[128][72];
  __shared__ __align__(16) _Float16 Bl[128][72];
  __shared__ float dvs[256];
  dvs[t] = (t < SS) ? dinv[b * SS + t] : 0.f;
  floatx4 acc[4][4] = {};
  const float* Ab  = A  + (size_t)b * SS * SS;
  const float* xwb = xw + (size_t)b * SS * HD;
  const int lr = t >> 1, lk = (t & 1) * 32;
  const int d = row0 + lr;
  __syncthreads();
  const float dvd = (d < SS) ? dvs[d] : 0.f;

  for (int k0 = 0; k0 < 256; k0 += 64) {
    __syncthreads();
    // ---- stage Ahat rows (hi/lo) ----
#pragma unroll
    for (int q = 0; q < 8; ++q) {
      int s = k0 + lk + q * 4;
      float4 v = {0.f, 0.f, 0.f, 0.f};
      if (d < SS && s < SS)
        v = *reinterpret_cast<const float4*>(&Ab[(size_t)d * SS + s]);
      float e0 = (v.x + ((s + 0 == d) ? 1.f : 0.f)) * dvd * dvs[(s + 0) & 255];
      float e1 = (v.y + ((s + 1 == d) ? 1.f : 0.f)) * dvd * dvs[(s + 1) & 255];
      float e2 = (v.z + ((s + 2 == d) ? 1.f : 0.f)) * dvd * dvs[(s + 2) & 255];
      float e3 = (v.w + ((s + 3 == d) ? 1.f : 0.f)) * dvd * dvs[(s + 3) & 255];
      half4v h = {(_Float16)e0, (_Float16)e1, (_Float16)e2, (_Float16)e3};
      half4v lo = {(_Float16)(e0 - (float)h.x), (_Float16)(e1 - (float)h.y),
                   (_Float16)(e2 - (float)h.z), (_Float16)(e3 - (float)h.w)};
      *reinterpret_cast<half4v*>(&Ah[lr][lk + q * 4]) = h;
      *reinterpret_cast<half4v*>(&Al[lr][lk + q * 4]) = lo;
    }
    // ---- stage xw transposed (hi/lo), XOR-swizzled ----
#pragma unroll
    for (int p = 0; p < 8; ++p) {
      int idx = t + p * 256;
      int c4 = idx & 31, ss = idx >> 5;          // ss 0..63
      int s = k0 + ss;
      float4 v = {0.f, 0.f, 0.f, 0.f};
      if (s < SS)
        v = *reinterpret_cast<const float4*>(&xwb[(size_t)s * HD + c4 * 4]);
      int ssx = ss ^ ((c4 & 7) << 3);            // (n>>2)&7 == c4&7 for n=4*c4+j
      float e[4] = {v.x, v.y, v.z, v.w};
#pragma unroll
      for (int j = 0; j < 4; ++j) {
        _Float16 h = (_Float16)e[j];
        Bh[c4 * 4 + j][ssx] = h;
        Bl[c4 * 4 + j][ssx] = (_Float16)(e[j] - (float)h);
      }
    }
    __syncthreads();
#pragma unroll
    for (int ks = 0; ks < 2; ++ks) {
      half8 ah[4], al[4], bh[4], bl[4];
#pragma unroll
      for (int i = 0; i < 4; ++i) {
        ah[i] = *reinterpret_cast<const half8*>(&Ah[wm + i * 16 + col][ks * 32 + quad * 8]);
        al[i] = *reinterpret_cast<const half8*>(&Al[wm + i * 16 + col][ks * 32 + quad * 8]);
      }
#pragma unroll
      for (int j = 0; j < 4; ++j) {
        int n = wn + j * 16 + col;
        int koff = (ks * 32 + quad * 8) ^ (((n >> 2) & 7) << 3);
        bh[j] = *reinterpret_cast<const half8*>(&Bh[n][koff]);
        bl[j] = *reinterpret_cast<const half8*>(&Bl[n][koff]);
      }
#pragma unroll
      for (int i = 0; i < 4; ++i)
#pragma unroll
        for (int j = 0; j < 4; ++j) {
          acc[i][j] = __builtin_amdgcn_mfma_f32_16x16x32_f16(ah[i], bh[j], acc[i][j], 0, 0, 0);
          acc[i][j] = __builtin_amdgcn_mfma_f32_16x16x32_f16(ah[i], bl[j], acc[i][j], 0, 0, 0);
          acc[i][j] = __builtin_amdgcn_mfma_f32_16x16x32_f16(al[i], bh[j], acc[i][j], 0, 0, 0);
        }
    }
  }
#pragma unroll
  for (int j = 0; j < 4; ++j) {
    int n = wn + j * 16 + col;
    float bb = bias[n];
#pragma unroll
    for (int i = 0; i < 4; ++i) {
      int rbase = row0 + wm + i * 16 + quad * 4;
#pragma unroll
      for (int r = 0; r < 4; ++r) {
        int row = rbase + r;
        if (row < SS)
          out[((size_t)b * SS + row) * HD + n] = tanhf(acc[i][j][r] + bb);
      }
    }
  }
}

// ---------------- SAGPool: score, top-k select, padded write ----------------
__global__ __launch_bounds__(256) void k_sag(
    const float* __restrict__ z, const float* __restrict__ A,
    const float* __restrict__ w1, const float* __restrict__ w2,
    const float* __restrict__ sb,
    __half* __restrict__ xch, __half* __restrict__ xcl, int layer) {
  const int b = blockIdx.x, t = threadIdx.x;
  __shared__ float w1s[HD], w2s[HD];
  __shared__ float zw1[SS], sc[SS], fac[SS];
  if (t < HD) { w1s[t] = w1[t]; w2s[t] = w2[t]; }
  __syncthreads();
  float a2 = 0.f;
  if (t < SS) {
    const float4* zr = reinterpret_cast<const float4*>(&z[((size_t)b * SS + t) * HD]);
    float a1 = 0.f;
#pragma unroll
    for (int q = 0; q < HD / 4; ++q) {
      float4 v = zr[q];
      a1 += v.x * w1s[4 * q] + v.y * w1s[4 * q + 1] + v.z * w1s[4 * q + 2] + v.w * w1s[4 * q + 3];
      a2 += v.x * w2s[4 * q] + v.y * w2s[4 * q + 1] + v.z * w2s[4 * q + 2] + v.w * w2s[4 * q + 3];
    }
    zw1[t] = a1;
  }
  __syncthreads();
  if (t < SS) {
    float s = sb[0] + a2;
    const float4* ar = reinterpret_cast<const float4*>(&A[((size_t)b * SS + t) * SS]);
#pragma unroll 5
    for (int q = 0; q < SS / 4; ++q) {
      float4 v = ar[q];
      s += v.x * zw1[4 * q] + v.y * zw1[4 * q + 1] + v.z * zw1[4 * q + 2] + v.w * zw1[4 * q + 3];
    }
    sc[t] = s;
  }
  __syncthreads();
  if (t < SS) {
    float si = sc[t];
    int cnt = 0;
    for (int j = 0; j < SS; ++j) {
      float sj = sc[j];
      cnt += (sj > si || (sj == si && j < t)) ? 1 : 0;
    }
    fac[t] = (cnt < TOPK) ? tanhf(si) : 0.f;
  }
  __syncthreads();
  _Float16* xh = (_Float16*)xch;
  _Float16* xl = (_Float16*)xcl;
  for (int idx = t; idx < SS * HD; idx += 256) {
    int row = idx >> 7, c = idx & 127;
    float v = fac[row] * z[((size_t)b * SS + row) * HD + c];
    _Float16 h = (_Float16)v;
    size_t o = ((size_t)b * SS + row) * EMB_ + layer * HD + c;
    xh[o] = h;
    xl[o] = (_Float16)(v - (float)h);
  }
}

// ------------- k_proj (m97 structure): QK = xc16 @ Win16^T + b --------------
// global_load_lds width-16 staging, linear LDS dest + inverse-swizzled global
// source + swizzled ds_read_b128 (rule #21). BK=64, 2-barrier K-loop.
// LDS content: As[row][c16] = Aglobal[row][c16 ^ (row&7)] (16B chunks).
__global__ __launch_bounds__(256) void k_proj(
    const __half* __restrict__ xch, const __half* __restrict__ Win16,
    const float* __restrict__ bin, __half* __restrict__ QKh) {
  const int wg = (blockIdx.x & 7) * 400 + (blockIdx.x >> 3);
  const int bm = wg >> 3;                // 0..399
  const int bn = wg & 7;                 // 0..7
  const int m0 = bm * 128, n0 = bn * 128;
  const int t = threadIdx.x;
  const int wave = t >> 6, lane = t & 63;
  const int col = lane & 15, quad = lane >> 4;
  const int wm = (wave & 1) * 64;
  const int wn = (wave >> 1) * 64;
  __shared__ __align__(16) _Float16 As[128][64];   // 16 KB, rows of 128 B
  __shared__ __align__(16) _Float16 Bs[128][64];   // 16 KB
  floatx4 acc[4][4] = {};
  const _Float16* X = (const _Float16*)xch;
  const _Float16* W = (const _Float16*)Win16;

  // staging geometry: call q, wave w, lane l writes LDS byte
  //   q*4096 + w*1024 + l*16  (HW: wave-uniform base + lane*16)
  //   -> row = q*32 + w*8 + (l>>3), chunk = l&7
  // source chunk = (l&7) ^ ((l>>3)&7)  (involution; row&7 == (l>>3)&7)
  const int srow = lane >> 3;                 // 0..7
  const int sch  = (lane & 7) ^ srow;         // swizzled source 16B-chunk
  const int arow = wave * 8 + srow;           // row within 32-row group, q adds 32
  // fragment read: row r, 16B chunk (ks*4+quad) ^ (r&7);  r&7 == col&7
  const int fsw = col & 7;

  for (int k0 = 0; k0 < EMB_; k0 += 64) {
#pragma unroll
    for (int q = 0; q < 4; ++q) {
      const _Float16* ga = X + (size_t)(m0 + q * 32 + arow) * EMB_ + k0 + sch * 8;
      __builtin_amdgcn_global_load_lds(
          (const __attribute__((address_space(1))) void*)ga,
          (__attribute__((address_space(3))) void*)((char*)&As[0][0] + q * 4096 + wave * 1024),
          16, 0, 0);
      const _Float16* gb = W + (size_t)(n0 + q * 32 + arow) * EMB_ + k0 + sch * 8;
      __builtin_amdgcn_global_load_lds(
          (const __attribute__((address_space(1))) void*)gb,
          (__attribute__((address_space(3))) void*)((char*)&Bs[0][0] + q * 4096 + wave * 1024),
          16, 0, 0);
    }
    __syncthreads();   // compiler emits vmcnt(0) drain before barrier
#pragma unroll
    for (int ks = 0; ks < 2; ++ks) {
      const int ch = (ks * 4 + quad) ^ fsw;    // swizzled 16B chunk
      half8 af[4], bf[4];
#pragma unroll
      for (int i = 0; i < 4; ++i)
        af[i] = *reinterpret_cast<const half8*>(
            (const char*)&As[0][0] + (wm + i * 16 + col) * 128 + ch * 16);
#pragma unroll
      for (int j = 0; j < 4; ++j)
        bf[j] = *reinterpret_cast<const half8*>(
            (const char*)&Bs[0][0] + (wn + j * 16 + col) * 128 + ch * 16);
#pragma unroll
      for (int i = 0; i < 4; ++i)
#pragma unroll
        for (int j = 0; j < 4; ++j)
          acc[i][j] = __builtin_amdgcn_mfma_f32_16x16x32_f16(af[i], bf[j], acc[i][j], 0, 0, 0);
    }
    __syncthreads();   // all reads done before next stage overwrites
  }
  // epilogue: C/D layout col=lane&15, row=quad*4+reg
#pragma unroll
  for (int j = 0; j < 4; ++j) {
    int c = n0 + wn + j * 16 + col;
    float bb = bin[c];
#pragma unroll
    for (int i = 0; i < 4; ++i) {
      int rbase = m0 + wm + i * 16 + quad * 4;
#pragma unroll
      for (int r = 0; r < 4; ++r)
        QKh[(size_t)(rbase + r) * 1024 + c] = __float2half(acc[i][j][r] + bb);
    }
  }
}

// ------------- k_attn (MFMA): block = (graph, 16-row tile) ------------------
__global__ __launch_bounds__(256) void k_attn(
    const __half* __restrict__ QKh,
    float* __restrict__ cpbuf,          // [B][8][200], pre-zeroed
    float* __restrict__ attn) {         // [B][200][200]
  const int bx = (blockIdx.x & 7) * 416 + (blockIdx.x >> 3);   // 3328 = 8*416
  const int b  = bx / 13;
  const int it = bx % 13;
  const int i0 = it * 16;
  const int rows = (SS - i0 >= 16) ? 16 : (SS - i0);   // 16 or 8
  const int t    = threadIdx.x;
  const int wave = t >> 6;
  const int lane = t & 63;
  const int col  = lane & 15;
  const int quad = lane >> 4;

  __shared__ __align__(16) float Ss[16][212];

  float am[13];
  int   soff[13];
  int   kmax = 0;
#pragma unroll
  for (int k = 0; k < 13; ++k) {
    int idx = t + (k << 8);
    am[k] = 0.f;
    if (idx < rows * 200) {
      int i = idx / 200;
      soff[k] = idx + 12 * i;
      kmax = k + 1;
    } else soff[k] = 0;
  }

  const _Float16* Qbase = (const _Float16*)QKh + (size_t)b * SS * 1024;
  const _Float16* qrow = Qbase + (size_t)(i0 + col) * 1024 + quad * 8;
  const _Float16* krow[4];
#pragma unroll
  for (int m = 0; m < 4; ++m) {
    int jt = wave + m * 4;
    krow[m] = Qbase + (size_t)(jt * 16 + col) * 1024 + 512 + quad * 8;
  }

  for (int h = 0; h < NHD; ++h) {
    const int hoff = h * 64;
    half8 a0 = *reinterpret_cast<const half8*>(qrow + hoff);
    half8 a1 = *reinterpret_cast<const half8*>(qrow + hoff + 32);
#pragma unroll
    for (int m = 0; m < 4; ++m) {
      int jt = wave + m * 4;
      if (jt < 13) {
        half8 b0 = *reinterpret_cast<const half8*>(krow[m] + hoff);
        half8 b1 = *reinterpret_cast<const half8*>(krow[m] + hoff + 32);
        floatx4 acc = {0.f, 0.f, 0.f, 0.f};
        acc = __builtin_amdgcn_mfma_f32_16x16x32_f16(a0, b0, acc, 0, 0, 0);
        acc = __builtin_amdgcn_mfma_f32_16x16x32_f16(a1, b1, acc, 0, 0, 0);
#pragma unroll
        for (int r = 0; r < 4; ++r)
          Ss[quad * 4 + r][jt * 16 + col] = acc[r] * 0.125f;
      }
    }
    __syncthreads();
#pragma unroll
    for (int ri = 0; ri < 4; ++ri) {
      int r = wave * 4 + ri;
      if (r < rows) {
        float* srow = &Ss[r][0];
        float s0 = srow[lane], s1 = srow[lane + 64], s2 = srow[lane + 128];
        float s3 = (lane < 8) ? srow[lane + 192] : -1e30f;
        float mx = fmaxf(fmaxf(s0, s1), fmaxf(s2, s3));
#pragma unroll
        for (int o = 32; o; o >>= 1) mx = fmaxf(mx, __shfl_xor(mx, o));
        float e0 = __expf(s0 - mx), e1 = __expf(s1 - mx), e2 = __expf(s2 - mx);
        float e3 = (lane < 8) ? __expf(s3 - mx) : 0.f;
        float sum = e0 + e1 + e2 + e3;
#pragma unroll
        for (int o = 32; o; o >>= 1) sum += __shfl_xor(sum, o);
        float rl = 1.0f / sum;
        srow[lane] = e0 * rl; srow[lane + 64] = e1 * rl; srow[lane + 128] = e2 * rl;
        if (lane < 8) srow[lane + 192] = e3 * rl;
      }
    }
    __syncthreads();
    const float* sflat = &Ss[0][0];
#pragma unroll
    for (int k = 0; k < 13; ++k)
      if (k < kmax) am[k] += sflat[soff[k]] * 0.125f;
    if (t < SS) {
      float s = 0.f;
      for (int i = 0; i < rows; ++i) s += Ss[i][t];
      atomicAdd(&cpbuf[((size_t)b * NHD + h) * SS + t], s);
    }
    __syncthreads();
  }
  float* abase = &attn[((size_t)b * SS + i0) * SS];
#pragma unroll
  for (int k = 0; k < 13; ++k)
    if (k < kmax) abase[t + (k << 8)] = am[k];
}

// ------------- k_pool: tvec_h = cp_h^T @ xc ; pooled = Wv tvec + bv*200 -----
__global__ __launch_bounds__(256) void k_pool(
    const __half* __restrict__ xch, const __half* __restrict__ xcl,
    const float* __restrict__ cpbuf,
    const float* __restrict__ Win, const float* __restrict__ bin,
    float* __restrict__ pooled) {
  const int b = blockIdx.x, t = threadIdx.x;
  __shared__ float cps[NHD][SS];
  __shared__ float tvs[NHD][EMB_];
  for (int idx = t; idx < NHD * SS; idx += 256) {
    int h = idx / SS, j = idx - h * SS;
    cps[h][j] = cpbuf[((size_t)b * NHD + h) * SS + j];
  }
  __syncthreads();
  const _Float16* xh = (const _Float16*)xch + (size_t)b * SS * EMB_;
  const _Float16* xl = (const _Float16*)xcl + (size_t)b * SS * EMB_;
  float a0[NHD] = {0.f}, a1[NHD] = {0.f};
  for (int j = 0; j < SS; ++j) {
    float x0 = (float)xh[(size_t)j * EMB_ + t] + (float)xl[(size_t)j * EMB_ + t];
    float x1 = (float)xh[(size_t)j * EMB_ + t + 256] + (float)xl[(size_t)j * EMB_ + t + 256];
#pragma unroll
    for (int h = 0; h < NHD; ++h) {
      float c = cps[h][j];
      a0[h] += c * x0; a1[h] += c * x1;
    }
  }
#pragma unroll
  for (int h = 0; h < NHD; ++h) { tvs[h][t] = a0[h]; tvs[h][t + 256] = a1[h]; }
  __syncthreads();
  const int wv = t >> 6, lane = t & 63;
  for (int e = wv; e < EMB_; e += 4) {
    int h = e >> 6;
    const float* wr = Win + (size_t)(2 * EMB_ + e) * EMB_;
    float s = 0.f;
#pragma unroll
    for (int q = 0; q < 8; ++q) s += wr[lane + q * 64] * tvs[h][lane + q * 64];
#pragma unroll
    for (int o = 32; o; o >>= 1) s += __shfl_xor(s, o);
    if (lane == 0) pooled[(size_t)b * EMB_ + e] = bin[2 * EMB_ + e] * (float)SS + s;
  }
}

// ---------------- readout ----------------
__global__ __launch_bounds__(256) void k_final(
    const float* __restrict__ pooled, const float* __restrict__ Wout,
    const float* __restrict__ bout, const float* __restrict__ finw,
    const float* __restrict__ finb, float* __restrict__ out) {
  const int b = blockIdx.x, t = threadIdx.x;
  __shared__ float pl[EMB_], po[EMB_];
  for (int k = t; k < EMB_; k += 256) pl[k] = pooled[(size_t)b * EMB_ + k] * (1.0f / (float)SS);
  __syncthreads();
  for (int e = t; e < EMB_; e += 256) {
    const float* wr = &Wout[(size_t)e * EMB_];
    float a = bout[e];
    for (int k = 0; k < EMB_; ++k) a += wr[k] * pl[k];
    po[e] = a;
  }
  __syncthreads();
  if (t < HD) {
    float a = finb[t];
    for (int e = 0; e < EMB_; ++e) a += po[e] * finw[(size_t)e * HD + t];
    out[(size_t)b * HD + t] = tanhf(a);
  }
}

// ---------------------------------------------------------------------------
extern "C" void kernel_launch(void* const* d_in, const int* in_sizes, int n_in,
                              void* d_out, int out_size, void* d_ws, size_t ws_size,
                              hipStream_t stream) {
  const float* x         = (const float*)d_in[0];
  const int*   ei        = (const int*)d_in[1];
  const float* gcn_w0    = (const float*)d_in[4];
  const float* gcn_w     = (const float*)d_in[5];
  const float* gcn_b     = (const float*)d_in[6];
  const float* lin1_w0   = (const float*)d_in[7];
  const float* lin1_w    = (const float*)d_in[8];
  const float* lin1_b    = (const float*)d_in[9];
  const float* lin2_w    = (const float*)d_in[10];
  const float* lin2_b    = (const float*)d_in[11];
  const float* sag_w1    = (const float*)d_in[12];
  const float* sag_w2    = (const float*)d_in[13];
  const float* sag_b     = (const float*)d_in[14];
  const float* mha_in_w  = (const float*)d_in[15];
  const float* mha_in_b  = (const float*)d_in[16];
  const float* mha_out_w = (const float*)d_in[17];
  const float* mha_out_b = (const float*)d_in[18];
  const float* fin_w     = (const float*)d_in[19];
  const float* fin_b     = (const float*)d_in[20];

  float* ws     = (float*)d_ws;
  float* dinv   = ws;                                  // 51,200
  float* Araw   = dinv + NT;                           // 10,240,000
  float* buf0   = Araw + (size_t)GB * SS * SS;         // 6,553,600
  float* buf1   = buf0 + (size_t)NT * HD;              // 6,553,600
  float* zbuf   = buf1 + (size_t)NT * HD;              // 6,553,600
  float* xcf    = zbuf + (size_t)NT * HD;              // 26,214,400-float region
  __half* xch   = (__half*)xcf;                        // [N][512] fp16 hi
  __half* xcl   = xch + (size_t)NT * EMB_;             // [N][512] fp16 lo
  float* pooled = xcf + (size_t)NT * EMB_;             // 131,072
  // QK (fp16) overlays [Araw .. zbuf-tail) once the GCN layers are done:
  __half* QKh  = (__half*)Araw;                        // 52,428,800 halves
  float* cpbuf = Araw + 26214400;                      // 409,600 floats (tail of overlay)

  float* outp = (float*)d_out;                         // [B,128]
  float* attn = outp + (size_t)GB * HD;                // [B,200,200]

  // transposed + hi/lo-split weights + fp16 Win live in the d_out attn region
  // (scratch only until k_attn fully overwrites it).
  __half* whi   = (__half*)attn;                       // 294,912 halves
  __half* wlo   = whi + 294912;                        // 294,912 halves
  __half* Win16 = wlo + 294912;                        // 524,288 halves

  hipMemsetAsync(Araw, 0, (size_t)GB * SS * SS * sizeof(float), stream);

  k_prep_all<<<12 * 128, 256, 0, stream>>>(gcn_w0, gcn_w, lin1_w0, lin1_w, lin2_w, whi, wlo);
  k_prep_w16<<<512, 256, 0, stream>>>(mha_in_w, Win16);
  k_build_A<<<NE_ / 256, 256, 0, stream>>>(ei, ei + NE_, Araw);
  k_dinv<<<NT / 4, 256, 0, stream>>>(Araw, dinv);

  static const int KPg[4]  = {256, 128, 128, 128};
  static const int KP1[4]  = {384, 256, 256, 256};
  static const int OFFg[4] = {0, 98304, 163840, 229376};
  static const int OFF1[4] = {32768, 114688, 180224, 245760};
  static const int OFF2[4] = {81920, 147456, 212992, 278528};

  for (int l = 0; l < NLAY; ++l) {
    const float* zin = (l == 0) ? x : zbuf;
    int k1 = (l == 0) ? KIN : HD;
    // xw = zin @ gcn_w          (no bias, no tanh)
    k_node_mfma<<<NT / 64, 256, 0, stream>>>(zin, k1, nullptr,
                                             whi + OFFg[l], wlo + OFFg[l], KPg[l],
                                             nullptr, buf0, 0);
    // x1 = tanh( Ahat @ xw + b )
    k_agg_mfma<<<GB * 2, 256, 0, stream>>>(Araw, dinv, buf0, gcn_b + l * HD, buf1);
    // h = tanh( [zin|x1] @ l1w + b )
    k_node_mfma<<<NT / 64, 256, 0, stream>>>(zin, k1, buf1,
                                             whi + OFF1[l], wlo + OFF1[l], KP1[l],
                                             lin1_b + l * HD, buf0, 1);
    // z = tanh( h @ l2w + b )
    k_node_mfma<<<NT / 64, 256, 0, stream>>>(buf0, HD, nullptr,
                                             whi + OFF2[l], wlo + OFF2[l], HD,
                                             lin2_b + l * HD, zbuf, 1);
    k_sag<<<GB, 256, 0, stream>>>(zbuf, Araw, sag_w1, sag_w2, sag_b, xch, xcl, l);
  }

  // ---- MHA ----
  hipMemsetAsync(cpbuf, 0, (size_t)GB * NHD * SS * sizeof(float), stream);
  k_proj<<<(NT / 128) * 8, 256, 0, stream>>>(xch, Win16, mha_in_b, QKh);
  k_attn<<<GB * 13, 256, 0, stream>>>(QKh, cpbuf, attn);
  k_pool<<<GB, 256, 0, stream>>>(xch, xcl, cpbuf, mha_in_w, mha_in_b, pooled);
  k_final<<<GB, 256, 0, stream>>>(pooled, mha_out_w, mha_out_b, fin_w, fin_b, outp);
}

// Round 5
// 1371.902 us; speedup vs baseline: 2.2909x; 1.0570x over previous
//
#include <hip/hip_runtime.h>
#include <hip/hip_fp16.h>

// ---------------------------------------------------------------------------
// GraphConv_8847632629923 : round 10
//   Post-mortem r9: top-5 only covers k_attn(186)+k_proj(~100); the GCN phase
//   aggregate (~1.1ms, 16 small GEMM launches) dominates. Fix: fuse the
//   row-local chain lin1 -> lin2 -> next-layer xw into ONE kernel per layer
//   (k_fused): h and z' stay in LDS (fp16 hi/lo, [64][136] stride = 2-way-free
//   banks); phases 2/3 have zero staging (A from LDS, B from L2 weights).
//   12 node launches -> 5 (xw0 + 4 fused); removes h round-trip (52 MB) and
//   z re-read. k_agg / k_sag / MHA kernels unchanged from round 9.
// ---------------------------------------------------------------------------

#define GB   256          // batch (graphs)
#define SS   200          // nodes per graph
#define KIN  200          // input features
#define HD   128          // hidden
#define NLAY 4
#define NHD  8
#define TOPK 100
#define NT   (GB * SS)    // 51200 nodes
#define EPG_ 6400
#define NE_  (GB * EPG_)  // 1,638,400 edges
#define EMB_ 512

typedef _Float16 half8 __attribute__((ext_vector_type(8)));
typedef _Float16 half4v __attribute__((ext_vector_type(4)));
typedef float floatx4 __attribute__((ext_vector_type(4)));

// ---------------- adjacency build ----------------
__global__ __launch_bounds__(256) void k_build_A(const int* __restrict__ src,
                                                 const int* __restrict__ dst,
                                                 float* __restrict__ A) {
  int e = blockIdx.x * 256 + threadIdx.x;
  if (e >= NE_) return;
  int d = dst[e], s = src[e];
  int b = d / SS;
  int dl = d - b * SS;
  int sl = s - b * SS;
  atomicAdd(&A[((size_t)b * SS + dl) * SS + sl], 1.0f);
}

// ---------------- dinv = rsqrt(in_deg + 1) ----------------
__global__ __launch_bounds__(256) void k_dinv(const float* __restrict__ A,
                                              float* __restrict__ dinv) {
  int node = blockIdx.x * 4 + (threadIdx.x >> 6);
  int lane = threadIdx.x & 63;
  const float* r = A + (size_t)node * SS;
  float v = r[lane] + r[lane + 64] + r[lane + 128];
  if (lane < 8) v += r[lane + 192];
#pragma unroll
  for (int o = 32; o; o >>= 1) v += __shfl_xor(v, o);
  if (lane == 0) dinv[node] = rsqrtf(v + 1.0f);
}

// ---------------- weight prep: transpose + fp16 hi/lo split -----------------
__global__ __launch_bounds__(256) void k_prep_all(
    const float* __restrict__ gcn_w0, const float* __restrict__ gcn_w,
    const float* __restrict__ lin1_w0, const float* __restrict__ lin1_w,
    const float* __restrict__ lin2_w,
    __half* __restrict__ whi, __half* __restrict__ wlo) {
  const int mat = blockIdx.x >> 7;   // 0..11
  const int n   = blockIdx.x & 127;
  const int l = mat / 3, which = mat % 3;
  const float* src;
  int K, Kpad;
  if (which == 0) {
    K = l ? HD : KIN;  Kpad = l ? 128 : 256;
    src = l ? gcn_w + (size_t)(l - 1) * HD * HD : gcn_w0;
  } else if (which == 1) {
    K = l ? 2 * HD : KIN + HD;  Kpad = l ? 256 : 384;
    src = l ? lin1_w + (size_t)(l - 1) * 2 * HD * HD : lin1_w0;
  } else {
    K = HD;  Kpad = HD;
    src = lin2_w + (size_t)l * HD * HD;
  }
  int off = (l == 0) ? (which == 0 ? 0 : (which == 1 ? 32768 : 81920))
                     : 98304 + (l - 1) * 65536 +
                       (which == 0 ? 0 : (which == 1 ? 16384 : 49152));
  _Float16* wh = (_Float16*)whi + (size_t)off + (size_t)n * Kpad;
  _Float16* wl = (_Float16*)wlo + (size_t)off + (size_t)n * Kpad;
  for (int k = threadIdx.x; k < Kpad; k += 256) {
    float v = (k < K) ? src[(size_t)k * HD + n] : 0.f;
    _Float16 h = (_Float16)v;
    wh[k] = h;
    wl[k] = (_Float16)(v - (float)h);
  }
}

// ---------------- Win (first 1024 rows of mha_in_w) -> fp16 -----------------
__global__ __launch_bounds__(256) void k_prep_w16(const float* __restrict__ W,
                                                  __half* __restrict__ W16) {
  int i = blockIdx.x * 256 + threadIdx.x;     // over 131072 float4s
  float4 v = reinterpret_cast<const float4*>(W)[i];
  half4v h = {(_Float16)v.x, (_Float16)v.y, (_Float16)v.z, (_Float16)v.w};
  *reinterpret_cast<half4v*>((_Float16*)W16 + (size_t)i * 4) = h;
}

// ------- node GEMM (MFMA split-fp16): out[N,128] = act([in1|in2]@W + b) -----
// (used only for xw0 = x @ gcn_w0 now)
__global__ __launch_bounds__(256) void k_node_mfma(
    const float* __restrict__ in1, int k1,
    const float* __restrict__ in2,                 // stride HD, may be null
    const __half* __restrict__ Whi, const __half* __restrict__ Wlo,
    int Kpad,
    const float* __restrict__ bias,                // may be null
    float* __restrict__ out, int doTanh) {
  const int m0 = blockIdx.x * 64;
  const int t = threadIdx.x;
  const int wave = t >> 6, lane = t & 63;
  const int col = lane & 15, quad = lane >> 4;
  const int wm = (wave & 1) * 32;
  const int wn = (wave >> 1) * 64;
  __shared__ __align__(16) _Float16 Ah[64][72];
  __shared__ __align__(16) _Float16 Al[64][72];
  floatx4 acc[2][4] = {};
  const int lr = t >> 2;              // staging row 0..63
  const int lk = (t & 3) * 16;        // staging k offset
  const _Float16* Wh = (const _Float16*)Whi;
  const _Float16* Wl = (const _Float16*)Wlo;

  for (int k0 = 0; k0 < Kpad; k0 += 64) {
    __syncthreads();
#pragma unroll
    for (int q = 0; q < 4; ++q) {
      int kg = k0 + lk + q * 4;
      float4 v = {0.f, 0.f, 0.f, 0.f};
      if (kg < k1)
        v = *reinterpret_cast<const float4*>(&in1[(size_t)(m0 + lr) * k1 + kg]);
      else if (in2 && kg < k1 + HD)
        v = *reinterpret_cast<const float4*>(&in2[(size_t)(m0 + lr) * HD + (kg - k1)]);
      half4v h = {(_Float16)v.x, (_Float16)v.y, (_Float16)v.z, (_Float16)v.w};
      half4v lo = {(_Float16)(v.x - (float)h.x), (_Float16)(v.y - (float)h.y),
                   (_Float16)(v.z - (float)h.z), (_Float16)(v.w - (float)h.w)};
      *reinterpret_cast<half4v*>(&Ah[lr][lk + q * 4]) = h;
      *reinterpret_cast<half4v*>(&Al[lr][lk + q * 4]) = lo;
    }
    __syncthreads();
#pragma unroll
    for (int ks = 0; ks < 2; ++ks) {
      half8 ah[2], al[2], bh[4], bl[4];
#pragma unroll
      for (int i = 0; i < 2; ++i) {
        ah[i] = *reinterpret_cast<const half8*>(&Ah[wm + i * 16 + col][ks * 32 + quad * 8]);
        al[i] = *reinterpret_cast<const half8*>(&Al[wm + i * 16 + col][ks * 32 + quad * 8]);
      }
#pragma unroll
      for (int j = 0; j < 4; ++j) {
        const size_t wo = (size_t)(wn + j * 16 + col) * Kpad + k0 + ks * 32 + quad * 8;
        bh[j] = *reinterpret_cast<const half8*>(Wh + wo);
        bl[j] = *reinterpret_cast<const half8*>(Wl + wo);
      }
#pragma unroll
      for (int i = 0; i < 2; ++i)
#pragma unroll
        for (int j = 0; j < 4; ++j) {
          acc[i][j] = __builtin_amdgcn_mfma_f32_16x16x32_f16(ah[i], bh[j], acc[i][j], 0, 0, 0);
          acc[i][j] = __builtin_amdgcn_mfma_f32_16x16x32_f16(ah[i], bl[j], acc[i][j], 0, 0, 0);
          acc[i][j] = __builtin_amdgcn_mfma_f32_16x16x32_f16(al[i], bh[j], acc[i][j], 0, 0, 0);
        }
    }
  }
#pragma unroll
  for (int j = 0; j < 4; ++j) {
    int n = wn + j * 16 + col;
    float bb = bias ? bias[n] : 0.f;
#pragma unroll
    for (int i = 0; i < 2; ++i) {
      int rbase = m0 + wm + i * 16 + quad * 4;
#pragma unroll
      for (int r = 0; r < 4; ++r) {
        float v = acc[i][j][r] + bb;
        if (doTanh) v = tanhf(v);
        out[(size_t)(rbase + r) * HD + n] = v;
      }
    }
  }
}

// ------- fused per-layer node chain: --------------------------------------
//   h  = tanh([z|x1] @ l1w + b1)        (phase 1, h -> LDS hi/lo)
//   z' = tanh(h @ l2w + b2)             (phase 2, z' -> global + LDS hi/lo)
//   xw'= z' @ gw'                       (phase 3, optional, -> global)
// 64-row block; A-frags for phases 2/3 from LDS [64][136] (2-way-free banks);
// B-frags direct from L2-resident pre-split weights.
__global__ __launch_bounds__(256) void k_fused(
    const float* __restrict__ in1, int k1,        // z (or x), [N][k1]
    const float* __restrict__ x1,                 // [N][128]
    const __half* __restrict__ l1wh, const __half* __restrict__ l1wl, int KP1,
    const float* __restrict__ l1b,
    const __half* __restrict__ l2wh, const __half* __restrict__ l2wl,
    const float* __restrict__ l2b,
    const __half* __restrict__ gwh, const __half* __restrict__ gwl, // may be null
    float* __restrict__ zout, float* __restrict__ xwout) {
  const int m0 = blockIdx.x * 64;
  const int t = threadIdx.x;
  const int wave = t >> 6, lane = t & 63;
  const int col = lane & 15, quad = lane >> 4;
  const int wm = (wave & 1) * 32;
  const int wn = (wave >> 1) * 64;
  __shared__ __align__(16) _Float16 Ah[64][72];
  __shared__ __align__(16) _Float16 Al[64][72];
  __shared__ __align__(16) _Float16 Hh[64][136];   // h, then z' (hi)
  __shared__ __align__(16) _Float16 Hl[64][136];   // h, then z' (lo)
  const int lr = t >> 2;
  const int lk = (t & 3) * 16;

  // ---------------- phase 1: h = tanh([z|x1] @ l1w + b1) ----------------
  {
    floatx4 acc[2][4] = {};
    for (int k0 = 0; k0 < KP1; k0 += 64) {
      __syncthreads();
#pragma unroll
      for (int q = 0; q < 4; ++q) {
        int kg = k0 + lk + q * 4;
        float4 v = {0.f, 0.f, 0.f, 0.f};
        if (kg < k1)
          v = *reinterpret_cast<const float4*>(&in1[(size_t)(m0 + lr) * k1 + kg]);
        else if (kg < k1 + HD)
          v = *reinterpret_cast<const float4*>(&x1[(size_t)(m0 + lr) * HD + (kg - k1)]);
        half4v h = {(_Float16)v.x, (_Float16)v.y, (_Float16)v.z, (_Float16)v.w};
        half4v lo = {(_Float16)(v.x - (float)h.x), (_Float16)(v.y - (float)h.y),
                     (_Float16)(v.z - (float)h.z), (_Float16)(v.w - (float)h.w)};
        *reinterpret_cast<half4v*>(&Ah[lr][lk + q * 4]) = h;
        *reinterpret_cast<half4v*>(&Al[lr][lk + q * 4]) = lo;
      }
      __syncthreads();
#pragma unroll
      for (int ks = 0; ks < 2; ++ks) {
        half8 ah[2], al[2], bh[4], bl[4];
#pragma unroll
        for (int i = 0; i < 2; ++i) {
          ah[i] = *reinterpret_cast<const half8*>(&Ah[wm + i * 16 + col][ks * 32 + quad * 8]);
          al[i] = *reinterpret_cast<const half8*>(&Al[wm + i * 16 + col][ks * 32 + quad * 8]);
        }
#pragma unroll
        for (int j = 0; j < 4; ++j) {
          const size_t wo = (size_t)(wn + j * 16 + col) * KP1 + k0 + ks * 32 + quad * 8;
          bh[j] = *reinterpret_cast<const half8*>((const _Float16*)l1wh + wo);
          bl[j] = *reinterpret_cast<const half8*>((const _Float16*)l1wl + wo);
        }
#pragma unroll
        for (int i = 0; i < 2; ++i)
#pragma unroll
          for (int j = 0; j < 4; ++j) {
            acc[i][j] = __builtin_amdgcn_mfma_f32_16x16x32_f16(ah[i], bh[j], acc[i][j], 0, 0, 0);
            acc[i][j] = __builtin_amdgcn_mfma_f32_16x16x32_f16(ah[i], bl[j], acc[i][j], 0, 0, 0);
            acc[i][j] = __builtin_amdgcn_mfma_f32_16x16x32_f16(al[i], bh[j], acc[i][j], 0, 0, 0);
          }
      }
    }
    // epilogue -> LDS h (hi/lo), tanh applied
#pragma unroll
    for (int j = 0; j < 4; ++j) {
      int n = wn + j * 16 + col;
      float bb = l1b[n];
#pragma unroll
      for (int i = 0; i < 2; ++i) {
        int rb = wm + i * 16 + quad * 4;
#pragma unroll
        for (int r = 0; r < 4; ++r) {
          float v = tanhf(acc[i][j][r] + bb);
          _Float16 h = (_Float16)v;
          Hh[rb + r][n] = h;
          Hl[rb + r][n] = (_Float16)(v - (float)h);
        }
      }
    }
  }
  __syncthreads();   // h visible to all waves

  // ---------------- phase 2: z' = tanh(h @ l2w + b2) ----------------
  {
    floatx4 acc[2][4] = {};
#pragma unroll
    for (int kc = 0; kc < 4; ++kc) {
      half8 ah[2], al[2], bh[4], bl[4];
#pragma unroll
      for (int i = 0; i < 2; ++i) {
        ah[i] = *reinterpret_cast<const half8*>(&Hh[wm + i * 16 + col][kc * 32 + quad * 8]);
        al[i] = *reinterpret_cast<const half8*>(&Hl[wm + i * 16 + col][kc * 32 + quad * 8]);
      }
#pragma unroll
      for (int j = 0; j < 4; ++j) {
        const size_t wo = (size_t)(wn + j * 16 + col) * HD + kc * 32 + quad * 8;
        bh[j] = *reinterpret_cast<const half8*>((const _Float16*)l2wh + wo);
        bl[j] = *reinterpret_cast<const half8*>((const _Float16*)l2wl + wo);
      }
#pragma unroll
      for (int i = 0; i < 2; ++i)
#pragma unroll
        for (int j = 0; j < 4; ++j) {
          acc[i][j] = __builtin_amdgcn_mfma_f32_16x16x32_f16(ah[i], bh[j], acc[i][j], 0, 0, 0);
          acc[i][j] = __builtin_amdgcn_mfma_f32_16x16x32_f16(ah[i], bl[j], acc[i][j], 0, 0, 0);
          acc[i][j] = __builtin_amdgcn_mfma_f32_16x16x32_f16(al[i], bh[j], acc[i][j], 0, 0, 0);
        }
    }
    __syncthreads();   // all h reads done before z' overwrites Hh/Hl
    // epilogue: write z' to global + LDS (hi/lo)
#pragma unroll
    for (int j = 0; j < 4; ++j) {
      int n = wn + j * 16 + col;
      float bb = l2b[n];
#pragma unroll
      for (int i = 0; i < 2; ++i) {
        int rb = wm + i * 16 + quad * 4;
#pragma unroll
        for (int r = 0; r < 4; ++r) {
          float v = tanhf(acc[i][j][r] + bb);
          zout[(size_t)(m0 + rb + r) * HD + n] = v;
          _Float16 h = (_Float16)v;
          Hh[rb + r][n] = h;
          Hl[rb + r][n] = (_Float16)(v - (float)h);
        }
      }
    }
  }
  if (!gwh) return;
  __syncthreads();   // z' visible to all waves

  // ---------------- phase 3: xw' = z' @ gw' ----------------
  {
    floatx4 acc[2][4] = {};
#pragma unroll
    for (int kc = 0; kc < 4; ++kc) {
      half8 ah[2], al[2], bh[4], bl[4];
#pragma unroll
      for (int i = 0; i < 2; ++i) {
        ah[i] = *reinterpret_cast<const half8*>(&Hh[wm + i * 16 + col][kc * 32 + quad * 8]);
        al[i] = *reinterpret_cast<const half8*>(&Hl[wm + i * 16 + col][kc * 32 + quad * 8]);
      }
#pragma unroll
      for (int j = 0; j < 4; ++j) {
        const size_t wo = (size_t)(wn + j * 16 + col) * HD + kc * 32 + quad * 8;
        bh[j] = *reinterpret_cast<const half8*>((const _Float16*)gwh + wo);
        bl[j] = *reinterpret_cast<const half8*>((const _Float16*)gwl + wo);
      }
#pragma unroll
      for (int i = 0; i < 2; ++i)
#pragma unroll
        for (int j = 0; j < 4; ++j) {
          acc[i][j] = __builtin_amdgcn_mfma_f32_16x16x32_f16(ah[i], bh[j], acc[i][j], 0, 0, 0);
          acc[i][j] = __builtin_amdgcn_mfma_f32_16x16x32_f16(ah[i], bl[j], acc[i][j], 0, 0, 0);
          acc[i][j] = __builtin_amdgcn_mfma_f32_16x16x32_f16(al[i], bh[j], acc[i][j], 0, 0, 0);
        }
    }
#pragma unroll
    for (int j = 0; j < 4; ++j) {
      int n = wn + j * 16 + col;
#pragma unroll
      for (int i = 0; i < 2; ++i) {
        int rb = wm + i * 16 + quad * 4;
#pragma unroll
        for (int r = 0; r < 4; ++r)
          xwout[(size_t)(m0 + rb + r) * HD + n] = acc[i][j][r];
      }
    }
  }
}

// ------- GCN aggregation (MFMA split-fp16): x1 = tanh( Ahat @ xw + b ) ------
__global__ __launch_bounds__(256) void k_agg_mfma(
    const float* __restrict__ A, const float* __restrict__ dinv,
    const float* __restrict__ xw, const float* __restrict__ bias,
    float* __restrict__ out) {
  const int b    = blockIdx.x >> 1;
  const int row0 = (blockIdx.x & 1) * 128;
  const int t = threadIdx.x;
  const int wave = t >> 6, lane = t & 63;
  const int col = lane & 15, quad = lane >> 4;
  const int wm = (wave & 1) * 64, wn = (wave >> 1) * 64;
  __shared__ __align__(16) _Float16 Ah[128][72];
  __shared__ __align__(16) _Float16 Al[128][72];
  __shared__ __align__(16) _Float16 Bh[128][72];
  __shared__ __align__(16) _Float16 Bl[128][72];
  __shared__ float dvs[256];
  dvs[t] = (t < SS) ? dinv[b * SS + t] : 0.f;
  floatx4 acc[4][4] = {};
  const float* Ab  = A  + (size_t)b * SS * SS;
  const float* xwb = xw + (size_t)b * SS * HD;
  const int lr = t >> 1, lk = (t & 1) * 32;
  const int d = row0 + lr;
  __syncthreads();
  const float dvd = (d < SS) ? dvs[d] : 0.f;

  for (int k0 = 0; k0 < 256; k0 += 64) {
    __syncthreads();
    // ---- stage Ahat rows (hi/lo) ----
#pragma unroll
    for (int q = 0; q < 8; ++q) {
      int s = k0 + lk + q * 4;
      float4 v = {0.f, 0.f, 0.f, 0.f};
      if (d < SS && s < SS)
        v = *reinterpret_cast<const float4*>(&Ab[(size_t)d * SS + s]);
      float e0 = (v.x + ((s + 0 == d) ? 1.f : 0.f)) * dvd * dvs[(s + 0) & 255];
      float e1 = (v.y + ((s + 1 == d) ? 1.f : 0.f)) * dvd * dvs[(s + 1) & 255];
      float e2 = (v.z + ((s + 2 == d) ? 1.f : 0.f)) * dvd * dvs[(s + 2) & 255];
      float e3 = (v.w + ((s + 3 == d) ? 1.f : 0.f)) * dvd * dvs[(s + 3) & 255];
      half4v h = {(_Float16)e0, (_Float16)e1, (_Float16)e2, (_Float16)e3};
      half4v lo = {(_Float16)(e0 - (float)h.x), (_Float16)(e1 - (float)h.y),
                   (_Float16)(e2 - (float)h.z), (_Float16)(e3 - (float)h.w)};
      *reinterpret_cast<half4v*>(&Ah[lr][lk + q * 4]) = h;
      *reinterpret_cast<half4v*>(&Al[lr][lk + q * 4]) = lo;
    }
    // ---- stage xw transposed (hi/lo), XOR-swizzled ----
#pragma unroll
    for (int p = 0; p < 8; ++p) {
      int idx = t + p * 256;
      int c4 = idx & 31, ss = idx >> 5;          // ss 0..63
      int s = k0 + ss;
      float4 v = {0.f, 0.f, 0.f, 0.f};
      if (s < SS)
        v = *reinterpret_cast<const float4*>(&xwb[(size_t)s * HD + c4 * 4]);
      int ssx = ss ^ ((c4 & 7) << 3);            // (n>>2)&7 == c4&7 for n=4*c4+j
      float e[4] = {v.x, v.y, v.z, v.w};
#pragma unroll
      for (int j = 0; j < 4; ++j) {
        _Float16 h = (_Float16)e[j];
        Bh[c4 * 4 + j][ssx] = h;
        Bl[c4 * 4 + j][ssx] = (_Float16)(e[j] - (float)h);
      }
    }
    __syncthreads();
#pragma unroll
    for (int ks = 0; ks < 2; ++ks) {
      half8 ah[4], al[4], bh[4], bl[4];
#pragma unroll
      for (int i = 0; i < 4; ++i) {
        ah[i] = *reinterpret_cast<const half8*>(&Ah[wm + i * 16 + col][ks * 32 + quad * 8]);
        al[i] = *reinterpret_cast<const half8*>(&Al[wm + i * 16 + col][ks * 32 + quad * 8]);
      }
#pragma unroll
      for (int j = 0; j < 4; ++j) {
        int n = wn + j * 16 + col;
        int koff = (ks * 32 + quad * 8) ^ (((n >> 2) & 7) << 3);
        bh[j] = *reinterpret_cast<const half8*>(&Bh[n][koff]);
        bl[j] = *reinterpret_cast<const half8*>(&Bl[n][koff]);
      }
#pragma unroll
      for (int i = 0; i < 4; ++i)
#pragma unroll
        for (int j = 0; j < 4; ++j) {
          acc[i][j] = __builtin_amdgcn_mfma_f32_16x16x32_f16(ah[i], bh[j], acc[i][j], 0, 0, 0);
          acc[i][j] = __builtin_amdgcn_mfma_f32_16x16x32_f16(ah[i], bl[j], acc[i][j], 0, 0, 0);
          acc[i][j] = __builtin_amdgcn_mfma_f32_16x16x32_f16(al[i], bh[j], acc[i][j], 0, 0, 0);
        }
    }
  }
#pragma unroll
  for (int j = 0; j < 4; ++j) {
    int n = wn + j * 16 + col;
    float bb = bias[n];
#pragma unroll
    for (int i = 0; i < 4; ++i) {
      int rbase = row0 + wm + i * 16 + quad * 4;
#pragma unroll
      for (int r = 0; r < 4; ++r) {
        int row = rbase + r;
        if (row < SS)
          out[((size_t)b * SS + row) * HD + n] = tanhf(acc[i][j][r] + bb);
      }
    }
  }
}

// ---------------- SAGPool: score, top-k select, padded write ----------------
__global__ __launch_bounds__(256) void k_sag(
    const float* __restrict__ z, const float* __restrict__ A,
    const float* __restrict__ w1, const float* __restrict__ w2,
    const float* __restrict__ sb,
    __half* __restrict__ xch, __half* __restrict__ xcl, int layer) {
  const int b = blockIdx.x, t = threadIdx.x;
  __shared__ float w1s[HD], w2s[HD];
  __shared__ float zw1[SS], sc[SS], fac[SS];
  if (t < HD) { w1s[t] = w1[t]; w2s[t] = w2[t]; }
  __syncthreads();
  float a2 = 0.f;
  if (t < SS) {
    const float4* zr = reinterpret_cast<const float4*>(&z[((size_t)b * SS + t) * HD]);
    float a1 = 0.f;
#pragma unroll
    for (int q = 0; q < HD / 4; ++q) {
      float4 v = zr[q];
      a1 += v.x * w1s[4 * q] + v.y * w1s[4 * q + 1] + v.z * w1s[4 * q + 2] + v.w * w1s[4 * q + 3];
      a2 += v.x * w2s[4 * q] + v.y * w2s[4 * q + 1] + v.z * w2s[4 * q + 2] + v.w * w2s[4 * q + 3];
    }
    zw1[t] = a1;
  }
  __syncthreads();
  if (t < SS) {
    float s = sb[0] + a2;
    const float4* ar = reinterpret_cast<const float4*>(&A[((size_t)b * SS + t) * SS]);
#pragma unroll 5
    for (int q = 0; q < SS / 4; ++q) {
      float4 v = ar[q];
      s += v.x * zw1[4 * q] + v.y * zw1[4 * q + 1] + v.z * zw1[4 * q + 2] + v.w * zw1[4 * q + 3];
    }
    sc[t] = s;
  }
  __syncthreads();
  if (t < SS) {
    float si = sc[t];
    int cnt = 0;
    for (int j = 0; j < SS; ++j) {
      float sj = sc[j];
      cnt += (sj > si || (sj == si && j < t)) ? 1 : 0;
    }
    fac[t] = (cnt < TOPK) ? tanhf(si) : 0.f;
  }
  __syncthreads();
  _Float16* xh = (_Float16*)xch;
  _Float16* xl = (_Float16*)xcl;
  for (int idx = t; idx < SS * HD; idx += 256) {
    int row = idx >> 7, c = idx & 127;
    float v = fac[row] * z[((size_t)b * SS + row) * HD + c];
    _Float16 h = (_Float16)v;
    size_t o = ((size_t)b * SS + row) * EMB_ + layer * HD + c;
    xh[o] = h;
    xl[o] = (_Float16)(v - (float)h);
  }
}

// ------------- k_proj (m97 structure): QK = xc16 @ Win16^T + b --------------
__global__ __launch_bounds__(256) void k_proj(
    const __half* __restrict__ xch, const __half* __restrict__ Win16,
    const float* __restrict__ bin, __half* __restrict__ QKh) {
  const int wg = (blockIdx.x & 7) * 400 + (blockIdx.x >> 3);
  const int bm = wg >> 3;                // 0..399
  const int bn = wg & 7;                 // 0..7
  const int m0 = bm * 128, n0 = bn * 128;
  const int t = threadIdx.x;
  const int wave = t >> 6, lane = t & 63;
  const int col = lane & 15, quad = lane >> 4;
  const int wm = (wave & 1) * 64;
  const int wn = (wave >> 1) * 64;
  __shared__ __align__(16) _Float16 As[128][64];   // 16 KB, rows of 128 B
  __shared__ __align__(16) _Float16 Bs[128][64];   // 16 KB
  floatx4 acc[4][4] = {};
  const _Float16* X = (const _Float16*)xch;
  const _Float16* W = (const _Float16*)Win16;

  const int srow = lane >> 3;                 // 0..7
  const int sch  = (lane & 7) ^ srow;         // swizzled source 16B-chunk
  const int arow = wave * 8 + srow;           // row within 32-row group
  const int fsw = col & 7;

  for (int k0 = 0; k0 < EMB_; k0 += 64) {
#pragma unroll
    for (int q = 0; q < 4; ++q) {
      const _Float16* ga = X + (size_t)(m0 + q * 32 + arow) * EMB_ + k0 + sch * 8;
      __builtin_amdgcn_global_load_lds(
          (const __attribute__((address_space(1))) void*)ga,
          (__attribute__((address_space(3))) void*)((char*)&As[0][0] + q * 4096 + wave * 1024),
          16, 0, 0);
      const _Float16* gb = W + (size_t)(n0 + q * 32 + arow) * EMB_ + k0 + sch * 8;
      __builtin_amdgcn_global_load_lds(
          (const __attribute__((address_space(1))) void*)gb,
          (__attribute__((address_space(3))) void*)((char*)&Bs[0][0] + q * 4096 + wave * 1024),
          16, 0, 0);
    }
    __syncthreads();
#pragma unroll
    for (int ks = 0; ks < 2; ++ks) {
      const int ch = (ks * 4 + quad) ^ fsw;    // swizzled 16B chunk
      half8 af[4], bf[4];
#pragma unroll
      for (int i = 0; i < 4; ++i)
        af[i] = *reinterpret_cast<const half8*>(
            (const char*)&As[0][0] + (wm + i * 16 + col) * 128 + ch * 16);
#pragma unroll
      for (int j = 0; j < 4; ++j)
        bf[j] = *reinterpret_cast<const half8*>(
            (const char*)&Bs[0][0] + (wn + j * 16 + col) * 128 + ch * 16);
#pragma unroll
      for (int i = 0; i < 4; ++i)
#pragma unroll
        for (int j = 0; j < 4; ++j)
          acc[i][j] = __builtin_amdgcn_mfma_f32_16x16x32_f16(af[i], bf[j], acc[i][j], 0, 0, 0);
    }
    __syncthreads();
  }
#pragma unroll
  for (int j = 0; j < 4; ++j) {
    int c = n0 + wn + j * 16 + col;
    float bb = bin[c];
#pragma unroll
    for (int i = 0; i < 4; ++i) {
      int rbase = m0 + wm + i * 16 + quad * 4;
#pragma unroll
      for (int r = 0; r < 4; ++r)
        QKh[(size_t)(rbase + r) * 1024 + c] = __float2half(acc[i][j][r] + bb);
    }
  }
}

// ------------- k_attn (MFMA): block = (graph, 16-row tile) ------------------
__global__ __launch_bounds__(256) void k_attn(
    const __half* __restrict__ QKh,
    float* __restrict__ cpbuf,          // [B][8][200], pre-zeroed
    float* __restrict__ attn) {         // [B][200][200]
  const int bx = (blockIdx.x & 7) * 416 + (blockIdx.x >> 3);   // 3328 = 8*416
  const int b  = bx / 13;
  const int it = bx % 13;
  const int i0 = it * 16;
  const int rows = (SS - i0 >= 16) ? 16 : (SS - i0);   // 16 or 8
  const int t    = threadIdx.x;
  const int wave = t >> 6;
  const int lane = t & 63;
  const int col  = lane & 15;
  const int quad = lane >> 4;

  __shared__ __align__(16) float Ss[16][212];

  float am[13];
  int   soff[13];
  int   kmax = 0;
#pragma unroll
  for (int k = 0; k < 13; ++k) {
    int idx = t + (k << 8);
    am[k] = 0.f;
    if (idx < rows * 200) {
      int i = idx / 200;
      soff[k] = idx + 12 * i;
      kmax = k + 1;
    } else soff[k] = 0;
  }

  const _Float16* Qbase = (const _Float16*)QKh + (size_t)b * SS * 1024;
  const _Float16* qrow = Qbase + (size_t)(i0 + col) * 1024 + quad * 8;
  const _Float16* krow[4];
#pragma unroll
  for (int m = 0; m < 4; ++m) {
    int jt = wave + m * 4;
    krow[m] = Qbase + (size_t)(jt * 16 + col) * 1024 + 512 + quad * 8;
  }

  for (int h = 0; h < NHD; ++h) {
    const int hoff = h * 64;
    half8 a0 = *reinterpret_cast<const half8*>(qrow + hoff);
    half8 a1 = *reinterpret_cast<const half8*>(qrow + hoff + 32);
#pragma unroll
    for (int m = 0; m < 4; ++m) {
      int jt = wave + m * 4;
      if (jt < 13) {
        half8 b0 = *reinterpret_cast<const half8*>(krow[m] + hoff);
        half8 b1 = *reinterpret_cast<const half8*>(krow[m] + hoff + 32);
        floatx4 acc = {0.f, 0.f, 0.f, 0.f};
        acc = __builtin_amdgcn_mfma_f32_16x16x32_f16(a0, b0, acc, 0, 0, 0);
        acc = __builtin_amdgcn_mfma_f32_16x16x32_f16(a1, b1, acc, 0, 0, 0);
#pragma unroll
        for (int r = 0; r < 4; ++r)
          Ss[quad * 4 + r][jt * 16 + col] = acc[r] * 0.125f;
      }
    }
    __syncthreads();
#pragma unroll
    for (int ri = 0; ri < 4; ++ri) {
      int r = wave * 4 + ri;
      if (r < rows) {
        float* srow = &Ss[r][0];
        float s0 = srow[lane], s1 = srow[lane + 64], s2 = srow[lane + 128];
        float s3 = (lane < 8) ? srow[lane + 192] : -1e30f;
        float mx = fmaxf(fmaxf(s0, s1), fmaxf(s2, s3));
#pragma unroll
        for (int o = 32; o; o >>= 1) mx = fmaxf(mx, __shfl_xor(mx, o));
        float e0 = __expf(s0 - mx), e1 = __expf(s1 - mx), e2 = __expf(s2 - mx);
        float e3 = (lane < 8) ? __expf(s3 - mx) : 0.f;
        float sum = e0 + e1 + e2 + e3;
#pragma unroll
        for (int o = 32; o; o >>= 1) sum += __shfl_xor(sum, o);
        float rl = 1.0f / sum;
        srow[lane] = e0 * rl; srow[lane + 64] = e1 * rl; srow[lane + 128] = e2 * rl;
        if (lane < 8) srow[lane + 192] = e3 * rl;
      }
    }
    __syncthreads();
    const float* sflat = &Ss[0][0];
#pragma unroll
    for (int k = 0; k < 13; ++k)
      if (k < kmax) am[k] += sflat[soff[k]] * 0.125f;
    if (t < SS) {
      float s = 0.f;
      for (int i = 0; i < rows; ++i) s += Ss[i][t];
      atomicAdd(&cpbuf[((size_t)b * NHD + h) * SS + t], s);
    }
    __syncthreads();
  }
  float* abase = &attn[((size_t)b * SS + i0) * SS];
#pragma unroll
  for (int k = 0; k < 13; ++k)
    if (k < kmax) abase[t + (k << 8)] = am[k];
}

// ------------- k_pool: tvec_h = cp_h^T @ xc ; pooled = Wv tvec + bv*200 -----
__global__ __launch_bounds__(256) void k_pool(
    const __half* __restrict__ xch, const __half* __restrict__ xcl,
    const float* __restrict__ cpbuf,
    const float* __restrict__ Win, const float* __restrict__ bin,
    float* __restrict__ pooled) {
  const int b = blockIdx.x, t = threadIdx.x;
  __shared__ float cps[NHD][SS];
  __shared__ float tvs[NHD][EMB_];
  for (int idx = t; idx < NHD * SS; idx += 256) {
    int h = idx / SS, j = idx - h * SS;
    cps[h][j] = cpbuf[((size_t)b * NHD + h) * SS + j];
  }
  __syncthreads();
  const _Float16* xh = (const _Float16*)xch + (size_t)b * SS * EMB_;
  const _Float16* xl = (const _Float16*)xcl + (size_t)b * SS * EMB_;
  float a0[NHD] = {0.f}, a1[NHD] = {0.f};
  for (int j = 0; j < SS; ++j) {
    float x0 = (float)xh[(size_t)j * EMB_ + t] + (float)xl[(size_t)j * EMB_ + t];
    float x1 = (float)xh[(size_t)j * EMB_ + t + 256] + (float)xl[(size_t)j * EMB_ + t + 256];
#pragma unroll
    for (int h = 0; h < NHD; ++h) {
      float c = cps[h][j];
      a0[h] += c * x0; a1[h] += c * x1;
    }
  }
#pragma unroll
  for (int h = 0; h < NHD; ++h) { tvs[h][t] = a0[h]; tvs[h][t + 256] = a1[h]; }
  __syncthreads();
  const int wv = t >> 6, lane = t & 63;
  for (int e = wv; e < EMB_; e += 4) {
    int h = e >> 6;
    const float* wr = Win + (size_t)(2 * EMB_ + e) * EMB_;
    float s = 0.f;
#pragma unroll
    for (int q = 0; q < 8; ++q) s += wr[lane + q * 64] * tvs[h][lane + q * 64];
#pragma unroll
    for (int o = 32; o; o >>= 1) s += __shfl_xor(s, o);
    if (lane == 0) pooled[(size_t)b * EMB_ + e] = bin[2 * EMB_ + e] * (float)SS + s;
  }
}

// ---------------- readout ----------------
__global__ __launch_bounds__(256) void k_final(
    const float* __restrict__ pooled, const float* __restrict__ Wout,
    const float* __restrict__ bout, const float* __restrict__ finw,
    const float* __restrict__ finb, float* __restrict__ out) {
  const int b = blockIdx.x, t = threadIdx.x;
  __shared__ float pl[EMB_], po[EMB_];
  for (int k = t; k < EMB_; k += 256) pl[k] = pooled[(size_t)b * EMB_ + k] * (1.0f / (float)SS);
  __syncthreads();
  for (int e = t; e < EMB_; e += 256) {
    const float* wr = &Wout[(size_t)e * EMB_];
    float a = bout[e];
    for (int k = 0; k < EMB_; ++k) a += wr[k] * pl[k];
    po[e] = a;
  }
  __syncthreads();
  if (t < HD) {
    float a = finb[t];
    for (int e = 0; e < EMB_; ++e) a += po[e] * finw[(size_t)e * HD + t];
    out[(size_t)b * HD + t] = tanhf(a);
  }
}

// ---------------------------------------------------------------------------
extern "C" void kernel_launch(void* const* d_in, const int* in_sizes, int n_in,
                              void* d_out, int out_size, void* d_ws, size_t ws_size,
                              hipStream_t stream) {
  const float* x         = (const float*)d_in[0];
  const int*   ei        = (const int*)d_in[1];
  const float* gcn_w0    = (const float*)d_in[4];
  const float* gcn_w     = (const float*)d_in[5];
  const float* gcn_b     = (const float*)d_in[6];
  const float* lin1_w0   = (const float*)d_in[7];
  const float* lin1_w    = (const float*)d_in[8];
  const float* lin1_b    = (const float*)d_in[9];
  const float* lin2_w    = (const float*)d_in[10];
  const float* lin2_b    = (const float*)d_in[11];
  const float* sag_w1    = (const float*)d_in[12];
  const float* sag_w2    = (const float*)d_in[13];
  const float* sag_b     = (const float*)d_in[14];
  const float* mha_in_w  = (const float*)d_in[15];
  const float* mha_in_b  = (const float*)d_in[16];
  const float* mha_out_w = (const float*)d_in[17];
  const float* mha_out_b = (const float*)d_in[18];
  const float* fin_w     = (const float*)d_in[19];
  const float* fin_b     = (const float*)d_in[20];

  float* ws     = (float*)d_ws;
  float* dinv   = ws;                                  // 51,200
  float* Araw   = dinv + NT;                           // 10,240,000
  float* buf0   = Araw + (size_t)GB * SS * SS;         // 6,553,600
  float* buf1   = buf0 + (size_t)NT * HD;              // 6,553,600
  float* zbuf   = buf1 + (size_t)NT * HD;              // 6,553,600
  float* xcf    = zbuf + (size_t)NT * HD;              // 26,214,400-float region
  __half* xch   = (__half*)xcf;                        // [N][512] fp16 hi
  __half* xcl   = xch + (size_t)NT * EMB_;             // [N][512] fp16 lo
  float* pooled = xcf + (size_t)NT * EMB_;             // 131,072
  // QK (fp16) overlays [Araw .. zbuf-tail) once the GCN layers are done:
  __half* QKh  = (__half*)Araw;                        // 52,428,800 halves
  float* cpbuf = Araw + 26214400;                      // 409,600 floats (tail of overlay)

  float* outp = (float*)d_out;                         // [B,128]
  float* attn = outp + (size_t)GB * HD;                // [B,200,200]

  // transposed + hi/lo-split weights + fp16 Win live in the d_out attn region
  // (scratch only until k_attn fully overwrites it).
  __half* whi   = (__half*)attn;                       // 294,912 halves
  __half* wlo   = whi + 294912;                        // 294,912 halves
  __half* Win16 = wlo + 294912;                        // 524,288 halves

  hipMemsetAsync(Araw, 0, (size_t)GB * SS * SS * sizeof(float), stream);

  k_prep_all<<<12 * 128, 256, 0, stream>>>(gcn_w0, gcn_w, lin1_w0, lin1_w, lin2_w, whi, wlo);
  k_prep_w16<<<512, 256, 0, stream>>>(mha_in_w, Win16);
  k_build_A<<<NE_ / 256, 256, 0, stream>>>(ei, ei + NE_, Araw);
  k_dinv<<<NT / 4, 256, 0, stream>>>(Araw, dinv);

  static const int KP1[4]  = {384, 256, 256, 256};
  static const int OFFg[4] = {0, 98304, 163840, 229376};
  static const int OFF1[4] = {32768, 114688, 180224, 245760};
  static const int OFF2[4] = {81920, 147456, 212992, 278528};

  // seed: xw0 = x @ gcn_w0
  k_node_mfma<<<NT / 64, 256, 0, stream>>>(x, KIN, nullptr,
                                           whi + OFFg[0], wlo + OFFg[0], 256,
                                           nullptr, buf0, 0);

  for (int l = 0; l < NLAY; ++l) {
    const float* zin = (l == 0) ? x : zbuf;
    int k1 = (l == 0) ? KIN : HD;
    // x1 = tanh( Ahat @ xw + b )          [buf0 -> buf1]
    k_agg_mfma<<<GB * 2, 256, 0, stream>>>(Araw, dinv, buf0, gcn_b + l * HD, buf1);
    // h = tanh([z|x1]@l1w+b); z' = tanh(h@l2w+b); xw' = z'@gw'   [-> zbuf, buf0]
    k_fused<<<NT / 64, 256, 0, stream>>>(
        zin, k1, buf1,
        whi + OFF1[l], wlo + OFF1[l], KP1[l], lin1_b + l * HD,
        whi + OFF2[l], wlo + OFF2[l], lin2_b + l * HD,
        (l < NLAY - 1) ? whi + OFFg[l + 1] : (const __half*)nullptr,
        (l < NLAY - 1) ? wlo + OFFg[l + 1] : (const __half*)nullptr,
        zbuf, buf0);
    k_sag<<<GB, 256, 0, stream>>>(zbuf, Araw, sag_w1, sag_w2, sag_b, xch, xcl, l);
  }

  // ---- MHA ----
  hipMemsetAsync(cpbuf, 0, (size_t)GB * NHD * SS * sizeof(float), stream);
  k_proj<<<(NT / 128) * 8, 256, 0, stream>>>(xch, Win16, mha_in_b, QKh);
  k_attn<<<GB * 13, 256, 0, stream>>>(QKh, cpbuf, attn);
  k_pool<<<GB, 256, 0, stream>>>(xch, xcl, cpbuf, mha_in_w, mha_in_b, pooled);
  k_final<<<GB, 256, 0, stream>>>(pooled, mha_out_w, mha_out_b, fin_w, fin_b, outp);
}